// Round 7
// baseline (649.062 us; speedup 1.0000x reference)
//
#include <hip/hip_runtime.h>

#define NVV 100000
#define NSV 50000
#define E_VV 1600000
#define E_H  800000
#define E_IN 800000
#define E_SS 800000
#define ETOT 4000000
#define DIN 5
#define H_ROW 100000          // concatenated cnt/rs space: vv|h|in|ss
#define IN_ROW 150000
#define SS_ROW 200000
#define NROWS 250000
#define POS_H  E_VV
#define POS_IN (E_VV + E_H)
#define POS_SS (E_VV + E_H + E_IN)
#define NBUK 196              // vv buckets (dst >> 9)
#define NBUKS 98              // NSV-graph buckets
#define NBTOT 490             // vv|h|in|ss bucket space
#define BUK_H  196
#define BUK_IN 294
#define BUK_SS 392
#define BSHIFT 9
#define T1 4096               // edges per fill-stage-1 block
#define TC 16384              // edges per bucket-count block
#define G1VV 391              // ceil(E_VV/T1)
#define G1S  196              // ceil(E_H/T1)
#define SB1  (G1VV + 3 * G1S) // 979 fused stage-1 blocks

__device__ __forceinline__ unsigned short f2bf(float x) {
  unsigned b = __float_as_uint(x);
  return (unsigned short)((b + 0x7FFFu + ((b >> 16) & 1u)) >> 16);
}
__device__ __forceinline__ float bf2f(unsigned short u) {
  return __uint_as_float(((unsigned)u) << 16);
}

// ====================== CSR build: bucket counts -> bases -> fused binned fills ======================

__global__ __launch_bounds__(256)
void k_bucket_count(const int* __restrict__ d_vv, const int* __restrict__ d_h,
                    const int* __restrict__ d_in, const int* __restrict__ d_ss,
                    int* __restrict__ bcnt) {
  __shared__ int h[NBTOT];
  const int tid = threadIdx.x;
  for (int i = tid; i < NBTOT; i += 256) h[i] = 0;
  __syncthreads();
  const int base = blockIdx.x * TC;
#pragma unroll 4
  for (int k = 0; k < TC / 256; k++) {
    int e = base + k * 256 + tid;
    int bi = -1;
    if (e < E_VV) bi = d_vv[e] >> BSHIFT;
    else if (e < POS_IN) bi = BUK_H + (d_h[e - POS_H] >> BSHIFT);
    else if (e < POS_SS) bi = BUK_IN + (d_in[e - POS_IN] >> BSHIFT);
    else if (e < ETOT) bi = BUK_SS + (d_ss[e - POS_SS] >> BSHIFT);
    if (bi >= 0) atomicAdd(&h[bi], 1);
  }
  __syncthreads();
  for (int i = tid; i < NBTOT; i += 256) if (h[i]) atomicAdd(&bcnt[i], h[i]);
}

__global__ __launch_bounds__(512)
void k_bucket_scan(const int* __restrict__ bcnt, int* __restrict__ bbase, int* __restrict__ cb) {
  __shared__ int sd[512];
  int t = threadIdx.x;
  int v = (t < NBTOT) ? bcnt[t] : 0;
  sd[t] = v; __syncthreads();
  for (int off = 1; off < 512; off <<= 1) {
    int x = (t >= off) ? sd[t - off] : 0;
    __syncthreads();
    sd[t] += x;
    __syncthreads();
  }
  int segstart = (t < BUK_H) ? 0 : (t < BUK_IN) ? BUK_H : (t < BUK_SS) ? BUK_IN : BUK_SS;
  int excl = ((t > 0) ? sd[t - 1] : 0) - ((segstart > 0) ? sd[segstart - 1] : 0);
  if (t < NBTOT) { bbase[t] = excl; cb[t] = excl; }
}

// ---- fused stage 1: all 4 graphs, bucket-grouped binning, coalesced run writes ----
__global__ __launch_bounds__(256)
void k_fill_s1_all(const int* __restrict__ s_vv, const int* __restrict__ d_vv,
                   const int* __restrict__ et,
                   const int* __restrict__ s_h, const int* __restrict__ d_h,
                   const float* __restrict__ ew,
                   const int* __restrict__ s_in, const int* __restrict__ d_in,
                   const int* __restrict__ s_ss, const int* __restrict__ d_ss,
                   int* __restrict__ cb,
                   unsigned* __restrict__ temp_vv, uint2* __restrict__ temp_h,
                   unsigned* __restrict__ temp_in, unsigned* __restrict__ temp_ss) {
  __shared__ int hist[NBUK], lbase[NBUK], run[NBUK], gb[NBUK];
  __shared__ int sc[256];
  __shared__ unsigned stage[T1];
  __shared__ unsigned stageW[T1];
  __shared__ int gpos[T1];
  const int tid = threadIdx.x;
  const int b = blockIdx.x;
  int g, tile;
  if (b < G1VV) { g = 0; tile = b; }
  else if (b < G1VV + G1S) { g = 1; tile = b - G1VV; }
  else if (b < G1VV + 2 * G1S) { g = 2; tile = b - G1VV - G1S; }
  else { g = 3; tile = b - G1VV - 2 * G1S; }
  const int ne = (g == 0) ? E_VV : E_H;
  const int nbuk = (g == 0) ? NBUK : NBUKS;
  const int cboff = (g == 0) ? 0 : (g == 1) ? BUK_H : (g == 2) ? BUK_IN : BUK_SS;
  const int* S = (g == 0) ? s_vv : (g == 1) ? s_h : (g == 2) ? s_in : s_ss;
  const int* D = (g == 0) ? d_vv : (g == 1) ? d_h : (g == 2) ? d_in : d_ss;
  const int base = tile * T1;
  const int nvalid = min(T1, ne - base);
  for (int i = tid; i < nbuk; i += 256) { hist[i] = 0; run[i] = 0; }
  __syncthreads();
  int dv[16]; unsigned pk[16], pkw[16];
#pragma unroll
  for (int k = 0; k < 16; k++) {
    int e = base + k * 256 + tid;
    if (e - base < nvalid) {
      int d = D[e];
      dv[k] = d;
      if (g == 0) pk[k] = (unsigned)(((d & 511) << 19) | (et[e] << 17) | S[e]);
      else pk[k] = (unsigned)(((d & 511) << 17) | S[e]);
      if (g == 1) pkw[k] = (unsigned)__float_as_int(ew[e]);
      atomicAdd(&hist[d >> BSHIFT], 1);
    } else dv[k] = -1;
  }
  __syncthreads();
  int my = (tid < nbuk) ? hist[tid] : 0;
  sc[tid] = my; __syncthreads();
  for (int off = 1; off < 256; off <<= 1) {
    int t = (tid >= off) ? sc[tid - off] : 0;
    __syncthreads();
    sc[tid] += t;
    __syncthreads();
  }
  if (tid < nbuk) {
    lbase[tid] = sc[tid] - my;
    gb[tid] = my ? atomicAdd(&cb[cboff + tid], my) : 0;
  }
  __syncthreads();
#pragma unroll
  for (int k = 0; k < 16; k++) {
    if (dv[k] >= 0) {
      int bu = dv[k] >> BSHIFT;
      int loc = atomicAdd(&run[bu], 1);
      int li = lbase[bu] + loc;
      stage[li] = pk[k];
      if (g == 1) stageW[li] = pkw[k];
      gpos[li] = gb[bu] + loc;
    }
  }
  __syncthreads();
  if (g == 0)      for (int i = tid; i < nvalid; i += 256) temp_vv[gpos[i]] = stage[i];
  else if (g == 1) for (int i = tid; i < nvalid; i += 256) temp_h[gpos[i]] = make_uint2(stage[i], stageW[i]);
  else if (g == 2) for (int i = tid; i < nvalid; i += 256) temp_in[gpos[i]] = stage[i];
  else             for (int i = tid; i < nvalid; i += 256) temp_ss[gpos[i]] = stage[i];
}

// ---- fused stage 2 ----
__global__ __launch_bounds__(256)
void k_fill_s2_all(const unsigned* __restrict__ temp_vv, const uint2* __restrict__ temp_h,
                   const unsigned* __restrict__ temp_in, const unsigned* __restrict__ temp_ss,
                   const int* __restrict__ bbase,
                   unsigned* __restrict__ payload_vv, int2* __restrict__ eh,
                   int* __restrict__ srcs_in, int* __restrict__ srcs_ss,
                   int* __restrict__ rs_all, int* __restrict__ cnt_all,
                   const float* __restrict__ x, float4* __restrict__ xp,
                   float* __restrict__ dinvS) {
  __shared__ int lcnt[512], lpos[512];
  __shared__ int sc[256];
  const int b = blockIdx.x, tid = threadIdx.x;
  int g, lb;
  if (b < BUK_H) { g = 0; lb = b; }
  else if (b < BUK_IN) { g = 1; lb = b - BUK_H; }
  else if (b < BUK_SS) { g = 2; lb = b - BUK_IN; }
  else { g = 3; lb = b - BUK_SS; }
  const int d0 = lb << BSHIFT;
  const int nrows = (g == 0) ? NVV : NSV;
  const int rowbase = (g == 0) ? 0 : (g == 1) ? H_ROW : (g == 2) ? IN_ROW : SS_ROW;
  const int ne = (g == 0) ? E_VV : E_H;
  const int lastb = (g == 0) ? NBUK - 1 : NBUKS - 1;
  const int shift = (g == 0) ? 19 : 17;
  lcnt[tid] = 0; lcnt[tid + 256] = 0;
  __syncthreads();
  const int gstart = bbase[b];
  const int gend = (lb == lastb) ? ne : bbase[b + 1];
  if (g == 1) {
    for (int i = gstart + tid; i < gend; i += 256) atomicAdd(&lcnt[temp_h[i].x >> 17], 1);
  } else {
    const unsigned* tp = (g == 0) ? temp_vv : (g == 2) ? temp_in : temp_ss;
    for (int i = gstart + tid; i < gend; i += 256) atomicAdd(&lcnt[tp[i] >> shift], 1);
  }
  __syncthreads();
  int c0 = lcnt[2 * tid], c1 = lcnt[2 * tid + 1];
  int ps = c0 + c1;
  sc[tid] = ps; __syncthreads();
  for (int off = 1; off < 256; off <<= 1) {
    int x2 = (tid >= off) ? sc[tid - off] : 0;
    __syncthreads();
    sc[tid] += x2;
    __syncthreads();
  }
  int basep = gstart + sc[tid] - ps;
  lpos[2 * tid] = basep;
  lpos[2 * tid + 1] = basep + c0;
  __syncthreads();
  for (int d = tid; d < 512; d += 256) {
    int gd = d0 + d;
    if (gd < nrows) {
      rs_all[rowbase + gd] = lpos[d];
      cnt_all[rowbase + gd] = lcnt[d];
      if (g == 0) {
        float dc = (float)lcnt[d];
        float di = dc > 0.f ? rsqrtf(dc) : 0.f;
        const float* xr = x + (size_t)gd * 5;
        xp[gd * 2]     = make_float4(xr[0], xr[1], xr[2], xr[3]);
        xp[gd * 2 + 1] = make_float4(xr[4], di, 0.f, 0.f);
      } else if (g == 3) {
        float dc = (float)lcnt[d];
        dinvS[gd] = dc > 0.f ? rsqrtf(dc) : 0.f;
      }
    }
  }
  __syncthreads();
  if (g == 0) {
    for (int i = gstart + tid; i < gend; i += 256) {
      unsigned en = temp_vv[i];
      int pos = atomicAdd(&lpos[en >> 19], 1);
      payload_vv[pos] = en & 0x7FFFFu;
    }
  } else if (g == 1) {
    for (int i = gstart + tid; i < gend; i += 256) {
      uint2 en = temp_h[i];
      int pos = atomicAdd(&lpos[en.x >> 17], 1);
      eh[pos] = make_int2((int)(en.x & 0x1FFFFu), (int)en.y);
    }
  } else if (g == 2) {
    for (int i = gstart + tid; i < gend; i += 256) {
      unsigned en = temp_in[i];
      int pos = atomicAdd(&lpos[en >> 17], 1);
      srcs_in[pos] = (int)(en & 0x1FFFFu);
    }
  } else {
    for (int i = gstart + tid; i < gend; i += 256) {
      unsigned en = temp_ss[i];
      int pos = atomicAdd(&lpos[en >> 17], 1);
      srcs_ss[pos] = (int)(en & 0x1FFFFu);
    }
  }
}

// ====================== Phase A: v-graph (5-dim, padded rows, 4 lanes/node) ======================

__global__ __launch_bounds__(256)
void k_vv_pass1(const float4* __restrict__ xp,
                const int* __restrict__ rowstart, const int* __restrict__ cnt,
                const unsigned* __restrict__ payload,
                float4* __restrict__ ra4all, float4* __restrict__ h1p) {
  const int tid = threadIdx.x;
  const int d = blockIdx.x * 64 + (tid >> 2);
  if (d >= NVV) return;
  const int q = tid & 3;
  int rs = rowstart[d], c = cnt[d];
  float a0[5] = {0,0,0,0,0}, a1[5] = {0,0,0,0,0}, a2[5] = {0,0,0,0,0}, h[5] = {0,0,0,0,0};
  float c0 = 0.f, c1 = 0.f, c2 = 0.f;
  int j = q;
  for (; j + 4 < c; j += 8) {
    unsigned pA = payload[rs + j], pB = payload[rs + j + 4];
    int sA = pA & 0x1FFFF, rA = pA >> 17;
    int sB = pB & 0x1FFFF, rB = pB >> 17;
    float4 xA0 = xp[sA * 2], xA1 = xp[sA * 2 + 1];
    float4 xB0 = xp[sB * 2], xB1 = xp[sB * 2 + 1];
    float xsA[5] = {xA0.x, xA0.y, xA0.z, xA0.w, xA1.x};
    float xsB[5] = {xB0.x, xB0.y, xB0.z, xB0.w, xB1.x};
    float wA = xA1.y, wB = xB1.y;
    float mA0 = (rA == 0) ? 1.f : 0.f, mA1 = (rA == 1) ? 1.f : 0.f, mA2 = (rA == 2) ? 1.f : 0.f;
    float mB0 = (rB == 0) ? 1.f : 0.f, mB1 = (rB == 1) ? 1.f : 0.f, mB2 = (rB == 2) ? 1.f : 0.f;
    c0 += mA0 + mB0; c1 += mA1 + mB1; c2 += mA2 + mB2;
#pragma unroll
    for (int k = 0; k < 5; k++) {
      h[k] += wA * xsA[k] + wB * xsB[k];
      a0[k] += mA0 * xsA[k] + mB0 * xsB[k];
      a1[k] += mA1 * xsA[k] + mB1 * xsB[k];
      a2[k] += mA2 * xsA[k] + mB2 * xsB[k];
    }
  }
  for (; j < c; j += 4) {
    unsigned p = payload[rs + j];
    int s = p & 0x1FFFF, r = p >> 17;
    float4 x0 = xp[s * 2], x1 = xp[s * 2 + 1];
    float xs[5] = {x0.x, x0.y, x0.z, x0.w, x1.x};
    float wsc = x1.y;
    float m0 = (r == 0) ? 1.f : 0.f, m1 = (r == 1) ? 1.f : 0.f, m2 = (r == 2) ? 1.f : 0.f;
    c0 += m0; c1 += m1; c2 += m2;
#pragma unroll
    for (int k = 0; k < 5; k++) {
      h[k] += wsc * xs[k];
      a0[k] += m0 * xs[k]; a1[k] += m1 * xs[k]; a2[k] += m2 * xs[k];
    }
  }
  // quad butterfly reduce: every lane ends with the full sums
#pragma unroll
  for (int k = 0; k < 5; k++) {
    a0[k] += __shfl_xor(a0[k], 1); a0[k] += __shfl_xor(a0[k], 2);
    a1[k] += __shfl_xor(a1[k], 1); a1[k] += __shfl_xor(a1[k], 2);
    a2[k] += __shfl_xor(a2[k], 1); a2[k] += __shfl_xor(a2[k], 2);
    h[k]  += __shfl_xor(h[k], 1);  h[k]  += __shfl_xor(h[k], 2);
  }
  c0 += __shfl_xor(c0, 1); c0 += __shfl_xor(c0, 2);
  c1 += __shfl_xor(c1, 1); c1 += __shfl_xor(c1, 2);
  c2 += __shfl_xor(c2, 1); c2 += __shfl_xor(c2, 2);
  float dv = xp[d * 2 + 1].y;
  float4* ra4 = ra4all + d * 5;
  if (q == 0) {
    ra4[0] = make_float4(a0[0], a0[1], a0[2], a0[3]);
    ra4[1] = make_float4(a0[4], a1[0], a1[1], a1[2]);
  } else if (q == 1) {
    ra4[2] = make_float4(a1[3], a1[4], a2[0], a2[1]);
    ra4[3] = make_float4(a2[2], a2[3], a2[4], c0);
  } else if (q == 2) {
    ra4[4] = make_float4(c1, c2, 0.f, 0.f);
  } else {
    h1p[d * 2]     = make_float4(dv * h[0], dv * h[1], dv * h[2], dv * h[3]);
    h1p[d * 2 + 1] = make_float4(dv * h[4], dv, 0.f, 0.f);
  }
}

__global__ __launch_bounds__(256)
void k_vv_hop(const float4* __restrict__ hinp,
              const int* __restrict__ rowstart, const int* __restrict__ cnt,
              const unsigned* __restrict__ payload, float4* __restrict__ houtp) {
  const int tid = threadIdx.x;
  const int d = blockIdx.x * 64 + (tid >> 2);
  if (d >= NVV) return;
  const int q = tid & 3;
  int rs = rowstart[d], c = cnt[d];
  float h[5] = {0,0,0,0,0};
  int j = q;
  for (; j + 4 < c; j += 8) {
    unsigned p0 = payload[rs + j], p1 = payload[rs + j + 4];
    int s0 = p0 & 0x1FFFF, s1 = p1 & 0x1FFFF;
    float4 a0 = hinp[s0 * 2], b0 = hinp[s0 * 2 + 1];
    float4 a1 = hinp[s1 * 2], b1 = hinp[s1 * 2 + 1];
    float w0 = b0.y, w1 = b1.y;
    h[0] += w0 * a0.x + w1 * a1.x;
    h[1] += w0 * a0.y + w1 * a1.y;
    h[2] += w0 * a0.z + w1 * a1.z;
    h[3] += w0 * a0.w + w1 * a1.w;
    h[4] += w0 * b0.x + w1 * b1.x;
  }
  for (; j < c; j += 4) {
    int s = payload[rs + j] & 0x1FFFF;
    float4 x0 = hinp[s * 2], x1 = hinp[s * 2 + 1];
    float wsc = x1.y;
    h[0] += wsc * x0.x; h[1] += wsc * x0.y; h[2] += wsc * x0.z; h[3] += wsc * x0.w;
    h[4] += wsc * x1.x;
  }
#pragma unroll
  for (int k = 0; k < 5; k++) {
    h[k] += __shfl_xor(h[k], 1);
    h[k] += __shfl_xor(h[k], 2);
  }
  float dv = hinp[d * 2 + 1].y;
  if (q == 0)      houtp[d * 2]     = make_float4(dv * h[0], dv * h[1], dv * h[2], dv * h[3]);
  else if (q == 1) houtp[d * 2 + 1] = make_float4(dv * h[4], dv, 0.f, 0.f);
}

// 8 nodes/thread, Ws column in 35 VGPRs, float4 relall loads.
__global__ __launch_bounds__(256)
void k_combine_gx(const float4* __restrict__ xp,
                  const float4* __restrict__ ra4all,
                  const float4* __restrict__ h1p, const float4* __restrict__ h2p,
                  const float4* __restrict__ h3p,
                  const float* __restrict__ W1_rel, const float* __restrict__ W1_root,
                  const float* __restrict__ b1,
                  const float* __restrict__ W12, const float* __restrict__ b12,
                  unsigned short* __restrict__ gx16) {
  __shared__ float Ws[7 * 320];
  __shared__ float bs[64];
  int tid = threadIdx.x;
  for (int i = tid; i < 320; i += 256) {
    Ws[i]        = W1_root[i] + W12[i];
    Ws[320 + i]  = W1_rel[i];
    Ws[640 + i]  = W1_rel[320 + i];
    Ws[960 + i]  = W1_rel[640 + i];
    Ws[1280 + i] = W12[320 + i];
    Ws[1600 + i] = W12[640 + i];
    Ws[1920 + i] = W12[960 + i];
  }
  if (tid < 64) bs[tid] = b1[tid] + b12[tid];
  __syncthreads();
  const int f = tid & 63;
  const int grp = tid >> 6;
  float wcol[35];
#pragma unroll
  for (int t = 0; t < 35; t++) wcol[t] = Ws[t * 64 + f];
  const float bias = bs[f];
  const int v0 = blockIdx.x * 32 + grp * 8;
  for (int n = 0; n < 8; n++) {
    int v = v0 + n;
    if (v >= NVV) return;
    float in[35];
    {
      float4 x0 = xp[v * 2], x1 = xp[v * 2 + 1];
      in[0] = x0.x; in[1] = x0.y; in[2] = x0.z; in[3] = x0.w; in[4] = x1.x;
    }
    {
      const float4* ra = ra4all + v * 5;
      float4 r0 = ra[0], r1 = ra[1], r2 = ra[2], r3 = ra[3], r4 = ra[4];
      float i0 = 1.0f / fmaxf(r3.w, 1.0f);
      float i1 = 1.0f / fmaxf(r4.x, 1.0f);
      float i2 = 1.0f / fmaxf(r4.y, 1.0f);
      in[5]  = r0.x * i0; in[6]  = r0.y * i0; in[7]  = r0.z * i0; in[8]  = r0.w * i0; in[9]  = r1.x * i0;
      in[10] = r1.y * i1; in[11] = r1.z * i1; in[12] = r1.w * i1; in[13] = r2.x * i1; in[14] = r2.y * i1;
      in[15] = r2.z * i2; in[16] = r2.w * i2; in[17] = r3.x * i2; in[18] = r3.y * i2; in[19] = r3.z * i2;
    }
    {
      float4 a = h1p[v * 2], b = h1p[v * 2 + 1];
      in[20] = a.x; in[21] = a.y; in[22] = a.z; in[23] = a.w; in[24] = b.x;
      a = h2p[v * 2]; b = h2p[v * 2 + 1];
      in[25] = a.x; in[26] = a.y; in[27] = a.z; in[28] = a.w; in[29] = b.x;
      a = h3p[v * 2]; b = h3p[v * 2 + 1];
      in[30] = a.x; in[31] = a.y; in[32] = a.z; in[33] = a.w; in[34] = b.x;
    }
    float acc = bias;
#pragma unroll
    for (int t = 0; t < 35; t++) acc += in[t] * wcol[t];
    gx16[v * 64 + f] = f2bf(acc);
  }
}

// ================= 64-dim CSR gathers (R3 dual-row packed form — verified) =================

__global__ __launch_bounds__(256)
void k_aggB(const unsigned short* __restrict__ X16,
            const int* __restrict__ rs_h, const int* __restrict__ cnt_h,
            const int2* __restrict__ eh,
            const int* __restrict__ rs_in, const int* __restrict__ cnt_in,
            const int* __restrict__ srcs_in,
            float* __restrict__ outw, float* __restrict__ outu, float* __restrict__ outIN,
            int nb64) {
  const unsigned* Xu = (const unsigned*)X16;
  int bb = blockIdx.x;
  int lane = threadIdx.x & 63;
  int q = lane & 31;
  int h = lane >> 5;                  // 0: even-slot edges, 1: odd-slot edges
  if (bb < nb64) {
    int wid = bb * 4 + (threadIdx.x >> 6);
    if (wid >= NSV) return;
    int rs = rs_h[wid], c = cnt_h[wid];
    int nh = (c - h + 1) >> 1;        // #edges for this half
    const int2* ep = eh + rs + h;     // stride-2 walk
    float au0 = 0.f, au1 = 0.f, aw0 = 0.f, aw1 = 0.f;
    int k = 0;
    for (; k + 4 <= nh; k += 4) {
      int2 p0 = ep[2 * k], p1 = ep[2 * k + 2], p2 = ep[2 * k + 4], p3 = ep[2 * k + 6];
      unsigned r0 = Xu[(unsigned)p0.x * 32 + q];
      unsigned r1 = Xu[(unsigned)p1.x * 32 + q];
      unsigned r2 = Xu[(unsigned)p2.x * 32 + q];
      unsigned r3 = Xu[(unsigned)p3.x * 32 + q];
      float w0 = __int_as_float(p0.y), w1 = __int_as_float(p1.y);
      float w2 = __int_as_float(p2.y), w3 = __int_as_float(p3.y);
      float l0 = __uint_as_float(r0 << 16), hi0 = __uint_as_float(r0 & 0xFFFF0000u);
      float l1 = __uint_as_float(r1 << 16), hi1 = __uint_as_float(r1 & 0xFFFF0000u);
      float l2 = __uint_as_float(r2 << 16), hi2 = __uint_as_float(r2 & 0xFFFF0000u);
      float l3 = __uint_as_float(r3 << 16), hi3 = __uint_as_float(r3 & 0xFFFF0000u);
      au0 += (l0 + l1) + (l2 + l3);
      au1 += (hi0 + hi1) + (hi2 + hi3);
      aw0 += w0 * l0 + w1 * l1 + w2 * l2 + w3 * l3;
      aw1 += w0 * hi0 + w1 * hi1 + w2 * hi2 + w3 * hi3;
    }
    for (; k < nh; k++) {
      int2 p = ep[2 * k];
      unsigned r = Xu[(unsigned)p.x * 32 + q];
      float w = __int_as_float(p.y);
      float lo = __uint_as_float(r << 16), hi = __uint_as_float(r & 0xFFFF0000u);
      au0 += lo; au1 += hi; aw0 += w * lo; aw1 += w * hi;
    }
    au0 += __shfl_xor(au0, 32); au1 += __shfl_xor(au1, 32);
    aw0 += __shfl_xor(aw0, 32); aw1 += __shfl_xor(aw1, 32);
    if (h == 0) {
      ((float2*)outw)[wid * 32 + q] = make_float2(aw0, aw1);
      ((float2*)outu)[wid * 32 + q] = make_float2(au0, au1);
    }
  } else {
    int wid = (bb - nb64) * 4 + (threadIdx.x >> 6);
    if (wid >= NSV) return;
    int rs = rs_in[wid], c = cnt_in[wid];
    int nh = (c - h + 1) >> 1;
    const int* sp = srcs_in + rs + h;
    float a0 = 0.f, a1 = 0.f;
    int k = 0;
    for (; k + 4 <= nh; k += 4) {
      int s0 = sp[2 * k], s1 = sp[2 * k + 2], s2 = sp[2 * k + 4], s3 = sp[2 * k + 6];
      unsigned r0 = Xu[(unsigned)s0 * 32 + q];
      unsigned r1 = Xu[(unsigned)s1 * 32 + q];
      unsigned r2 = Xu[(unsigned)s2 * 32 + q];
      unsigned r3 = Xu[(unsigned)s3 * 32 + q];
      a0 += (__uint_as_float(r0 << 16) + __uint_as_float(r1 << 16))
          + (__uint_as_float(r2 << 16) + __uint_as_float(r3 << 16));
      a1 += (__uint_as_float(r0 & 0xFFFF0000u) + __uint_as_float(r1 & 0xFFFF0000u))
          + (__uint_as_float(r2 & 0xFFFF0000u) + __uint_as_float(r3 & 0xFFFF0000u));
    }
    for (; k < nh; k++) {
      unsigned r = Xu[(unsigned)sp[2 * k] * 32 + q];
      a0 += __uint_as_float(r << 16);
      a1 += __uint_as_float(r & 0xFFFF0000u);
    }
    a0 += __shfl_xor(a0, 32); a1 += __shfl_xor(a1, 32);
    if (h == 0) ((float2*)outIN)[wid * 32 + q] = make_float2(a0, a1);
  }
}

// prescaled TAG hop: U = dinv ⊙ t (bf16). t_out = dinv[d]*Σ U[s]; u_out = dinv[d]*t_out.
__global__ __launch_bounds__(256)
void k_tag64b(const unsigned short* __restrict__ U16,
              const int* __restrict__ rowstart, const int* __restrict__ cnt,
              const int* __restrict__ srcs, const float* __restrict__ dinv,
              unsigned short* __restrict__ t_out, unsigned short* __restrict__ u_out, int n) {
  const unsigned* Xu = (const unsigned*)U16;
  int wid = blockIdx.x * 4 + (threadIdx.x >> 6);
  if (wid >= n) return;
  int lane = threadIdx.x & 63;
  int q = lane & 31;
  int h = lane >> 5;
  int rs = rowstart[wid], c = cnt[wid];
  int nh = (c - h + 1) >> 1;
  const int* sp = srcs + rs + h;
  float a0 = 0.f, a1 = 0.f;
  int k = 0;
  for (; k + 4 <= nh; k += 4) {
    int s0 = sp[2 * k], s1 = sp[2 * k + 2], s2 = sp[2 * k + 4], s3 = sp[2 * k + 6];
    unsigned r0 = Xu[(unsigned)s0 * 32 + q];
    unsigned r1 = Xu[(unsigned)s1 * 32 + q];
    unsigned r2 = Xu[(unsigned)s2 * 32 + q];
    unsigned r3 = Xu[(unsigned)s3 * 32 + q];
    a0 += (__uint_as_float(r0 << 16) + __uint_as_float(r1 << 16))
        + (__uint_as_float(r2 << 16) + __uint_as_float(r3 << 16));
    a1 += (__uint_as_float(r0 & 0xFFFF0000u) + __uint_as_float(r1 & 0xFFFF0000u))
        + (__uint_as_float(r2 & 0xFFFF0000u) + __uint_as_float(r3 & 0xFFFF0000u));
  }
  for (; k < nh; k++) {
    unsigned r = Xu[(unsigned)sp[2 * k] * 32 + q];
    a0 += __uint_as_float(r << 16);
    a1 += __uint_as_float(r & 0xFFFF0000u);
  }
  a0 += __shfl_xor(a0, 32); a1 += __shfl_xor(a1, 32);
  if (h == 0) {
    float dv = dinv[wid];
    float t0 = dv * a0, t1 = dv * a1;
    ((unsigned*)t_out)[wid * 32 + q] = (unsigned)f2bf(t0) | ((unsigned)f2bf(t1) << 16);
    if (u_out)
      ((unsigned*)u_out)[wid * 32 + q] = (unsigned)f2bf(dv * t0) | ((unsigned)f2bf(dv * t1) << 16);
  }
}

// ====================== Fused MM building blocks (256 threads, 4 nodes x 4 feats) ======================
// NOTE (r12-r14): 512-thread variants produced ~2-4 GB phantom scratch traffic. Keep 256.
// NOTE (R1): named-register T14 queues + __launch_bounds__(256,3) — do not revert to arrays.
// NOTE (R6): R3's scalar mm_acc (broadcast A-reads) is the verified-best form:
// R3=63.4us vs R4 K-major=66.6us vs R5 k-vectorized=69.4us.
// NOTE (R7): k_agg64b FUSED into k_mm_e (stream-level serialization removed: blocks
// gather their own 64 rows of aggSS from S1b directly into `as`, overlapping other
// blocks' MM phases device-wide; deletes one launch + 12.8MB aggSS round-trip).

__device__ __forceinline__ void mm_zero(float acc[4][4]) {
#pragma unroll
  for (int j = 0; j < 4; j++)
#pragma unroll
    for (int jj = 0; jj < 4; jj++) acc[j][jj] = 0.f;
}

__device__ __forceinline__ void mm_acc(const float* sA, const float* sW, int K,
                                       int nl0, int f0, float acc[4][4]) {
  for (int k = 0; k < K; k++) {
    float4 w = *(const float4*)(&sW[k * 64 + f0]);
#pragma unroll
    for (int j = 0; j < 4; j++) {
      float a = sA[(nl0 + j) * 68 + k];
      acc[j][0] += a * w.x; acc[j][1] += a * w.y; acc[j][2] += a * w.z; acc[j][3] += a * w.w;
    }
  }
}

// ---- named-register staging queue (single set live at a time) ----
#define WQ_ISSUE(W) do { const float4* _w = (const float4*)(W); \
  sw0 = _w[tid]; sw1 = _w[tid + 256]; sw2 = _w[tid + 512]; sw3 = _w[tid + 768]; } while (0)

#define WQ_COMMIT() do { float4* _s = (float4*)Ws; \
  _s[tid] = sw0; _s[tid + 256] = sw1; _s[tid + 512] = sw2; _s[tid + 768] = sw3; } while (0)

#define AQ_ISSUE1_F32(A, CNT, aa, cc, I) do { int _idx = tid + (I) * 256; \
  int _nl = _idx >> 4, _k4 = _idx & 15; int _g = gb + _nl; bool _ok = _g < n; \
  (aa) = _ok ? ((const float4*)(A))[_g * 16 + _k4] : make_float4(0.f, 0.f, 0.f, 0.f); \
  (cc) = ((CNT) != nullptr && _ok) ? (float)(CNT)[_g] : 1.f; } while (0)

#define AQ_ISSUE_F32(A, CNT) do { \
  AQ_ISSUE1_F32(A, CNT, sa0, sc0, 0); AQ_ISSUE1_F32(A, CNT, sa1, sc1, 1); \
  AQ_ISSUE1_F32(A, CNT, sa2, sc2, 2); AQ_ISSUE1_F32(A, CNT, sa3, sc3, 3); } while (0)

#define AQ_COMMIT1_F32(DST, SC, aa, cc, I) do { int _idx = tid + (I) * 256; \
  int _nl = _idx >> 4, _k4 = _idx & 15; float4 _v = (aa); \
  if (SC) { float _m = 1.f / fmaxf((cc), 1.f); _v.x *= _m; _v.y *= _m; _v.z *= _m; _v.w *= _m; } \
  *(float4*)(&(DST)[_nl * 68 + _k4 * 4]) = _v; } while (0)

#define AQ_COMMIT_F32(DST, SC) do { \
  AQ_COMMIT1_F32(DST, SC, sa0, sc0, 0); AQ_COMMIT1_F32(DST, SC, sa1, sc1, 1); \
  AQ_COMMIT1_F32(DST, SC, sa2, sc2, 2); AQ_COMMIT1_F32(DST, SC, sa3, sc3, 3); } while (0)

#define AQ_ISSUE1_BF16(A, bb, I) do { int _idx = tid + (I) * 256; \
  int _nl = _idx >> 4, _k4 = _idx & 15; int _g = gb + _nl; \
  (bb) = (_g < n) ? ((const uint2*)((A) + (size_t)_g * 64))[_k4] : make_uint2(0u, 0u); } while (0)

#define AQ_ISSUE_BF16(A) do { \
  AQ_ISSUE1_BF16(A, sb0, 0); AQ_ISSUE1_BF16(A, sb1, 1); \
  AQ_ISSUE1_BF16(A, sb2, 2); AQ_ISSUE1_BF16(A, sb3, 3); } while (0)

#define AQ_COMMIT1_BF16(bb, I) do { int _idx = tid + (I) * 256; \
  int _nl = _idx >> 4, _k4 = _idx & 15; float4 _v; \
  _v.x = bf2f((unsigned short)((bb).x & 0xFFFF)); \
  _v.y = bf2f((unsigned short)((bb).x >> 16)); \
  _v.z = bf2f((unsigned short)((bb).y & 0xFFFF)); \
  _v.w = bf2f((unsigned short)((bb).y >> 16)); \
  *(float4*)(&as[_nl * 68 + _k4 * 4]) = _v; } while (0)

#define AQ_COMMIT_BF16() do { \
  AQ_COMMIT1_BF16(sb0, 0); AQ_COMMIT1_BF16(sb1, 1); \
  AQ_COMMIT1_BF16(sb2, 2); AQ_COMMIT1_BF16(sb3, 3); } while (0)

// ---- phase-C chain: S2 = relu(aggIN'@W42_l + relu(aggIN'@W4_l + relu(aggHu'@W32_l +
//      relu(aggHw@W3_rel + sx@W3_root + b3)@W32_r + b32)@W4_r + b4)@W42_r + b42) ----
__global__ __launch_bounds__(256, 3)
void k_mm_chainC(const float* __restrict__ aggHw, const float* __restrict__ state_x,
                 const float* __restrict__ aggHu, const int* __restrict__ cnt_h,
                 const float* __restrict__ aggIN, const int* __restrict__ cnt_in,
                 const float* __restrict__ W3_rel, const float* __restrict__ W3_root,
                 const float* __restrict__ b3,
                 const float* __restrict__ W32_l, const float* __restrict__ W32_r,
                 const float* __restrict__ b32,
                 const float* __restrict__ W4_l, const float* __restrict__ W4_r,
                 const float* __restrict__ b4,
                 const float* __restrict__ W42_l, const float* __restrict__ W42_r,
                 const float* __restrict__ b42,
                 float* __restrict__ S2out, unsigned short* __restrict__ S2b,
                 const float* __restrict__ dinvS, int n) {
  __shared__ float Ws[4096];
  __shared__ float as[64 * 68];
  __shared__ float cs[64 * 68];
  const int tid = threadIdx.x;
  const int gb = blockIdx.x * 64;
  const int lane = tid & 63;
  const int fq = lane & 15, nq = lane >> 4;
  const int f0 = fq * 4;
  const int nl0 = (tid >> 6) * 16 + nq * 4;
  float acc[4][4];
  float4 sw0, sw1, sw2, sw3, sa0, sa1, sa2, sa3;
  float sc0, sc1, sc2, sc3;

  // ---- prologue: stage1 + all small scalars ----
  WQ_ISSUE(W3_rel);
  AQ_ISSUE_F32(aggHw, (const int*)nullptr);
  float rt0 = W3_root[tid];
  float rt1 = (tid < 64) ? W3_root[256 + tid] : 0.f;
  const int nlA = tid / 5, kA = tid - nlA * 5;
  float sxA = (gb + nlA < n) ? state_x[(size_t)(gb + nlA) * 5 + kA] : 0.f;
  const int iB = tid + 256;
  const int nlB = iB / 5, kB = iB - nlB * 5;
  float sxB = (tid < 64 && gb + nlB < n) ? state_x[(size_t)(gb + nlB) * 5 + kB] : 0.f;
  float4 rb3  = ((const float4*)b3)[fq];
  float4 rb32 = ((const float4*)b32)[fq];
  float4 rb4  = ((const float4*)b4)[fq];
  float4 rb42 = ((const float4*)b42)[fq];
  float rdv[4];
#pragma unroll
  for (int j = 0; j < 4; j++) {
    int g = gb + nl0 + j;
    rdv[j] = (g < n) ? dinvS[g] : 0.f;
  }
  WQ_COMMIT();                       // Ws <- W3_rel
  AQ_COMMIT_F32(as, false);          // as <- aggHw
  __syncthreads();

  // ---- phase 1: C1a + C1b ----
  WQ_ISSUE(W32_l);
  AQ_ISSUE_F32(aggHu, cnt_h);        // in flight under C1a+C1b
  mm_zero(acc);
  mm_acc(as, Ws, 64, nl0, f0, acc);  // C1a: aggHw @ W3_rel
  __syncthreads();
  Ws[tid] = rt0;                     // small commit: W3_root, state_x
  if (tid < 64) Ws[256 + tid] = rt1;
  as[nlA * 68 + kA] = sxA;
  if (tid < 64) as[nlB * 68 + kB] = sxB;
  __syncthreads();
  mm_acc(as, Ws, 5, nl0, f0, acc);   // C1b: + state_x @ W3_root
  {
    float bb[4] = {rb3.x, rb3.y, rb3.z, rb3.w};
#pragma unroll
    for (int j = 0; j < 4; j++)
#pragma unroll
      for (int jj = 0; jj < 4; jj++)
        cs[(nl0 + j) * 68 + f0 + jj] = fmaxf(acc[j][jj] + bb[jj], 0.f);
  }
  __syncthreads();
  WQ_COMMIT();                       // Ws <- W32_l
  AQ_COMMIT_F32(as, true);           // as <- aggHu'
  __syncthreads();

  // ---- phase 2: C2a ----
  WQ_ISSUE(W32_r);                   // in flight under C2a
  mm_zero(acc);
  mm_acc(as, Ws, 64, nl0, f0, acc);  // aggHu' @ W32_l
  __syncthreads();
  WQ_COMMIT();                       // Ws <- W32_r
  __syncthreads();

  // ---- phase 3: C2b ----
  WQ_ISSUE(W4_l);
  AQ_ISSUE_F32(aggIN, cnt_in);       // in flight under C2b
  mm_acc(cs, Ws, 64, nl0, f0, acc);  // + h3 @ W32_r
  __syncthreads();
  {
    float bb[4] = {rb32.x, rb32.y, rb32.z, rb32.w};
#pragma unroll
    for (int j = 0; j < 4; j++)
#pragma unroll
      for (int jj = 0; jj < 4; jj++)
        cs[(nl0 + j) * 68 + f0 + jj] = fmaxf(acc[j][jj] + bb[jj], 0.f);
  }
  WQ_COMMIT();                       // Ws <- W4_l
  AQ_COMMIT_F32(as, true);           // as <- aggIN' (lives through C4a)
  __syncthreads();

  // ---- phase 4: C3a ----
  WQ_ISSUE(W4_r);
  mm_zero(acc);
  mm_acc(as, Ws, 64, nl0, f0, acc);  // aggIN' @ W4_l
  __syncthreads();
  WQ_COMMIT();                       // Ws <- W4_r
  __syncthreads();

  // ---- phase 5: C3b ----
  WQ_ISSUE(W42_l);
  mm_acc(cs, Ws, 64, nl0, f0, acc);  // + h32 @ W4_r
  __syncthreads();
  {
    float bb[4] = {rb4.x, rb4.y, rb4.z, rb4.w};
#pragma unroll
    for (int j = 0; j < 4; j++)
#pragma unroll
      for (int jj = 0; jj < 4; jj++)
        cs[(nl0 + j) * 68 + f0 + jj] = fmaxf(acc[j][jj] + bb[jj], 0.f);
  }
  WQ_COMMIT();                       // Ws <- W42_l
  __syncthreads();

  // ---- phase 6: C4a ----
  WQ_ISSUE(W42_r);
  mm_zero(acc);
  mm_acc(as, Ws, 64, nl0, f0, acc);  // aggIN' @ W42_l (as untouched since phase 3)
  __syncthreads();
  WQ_COMMIT();                       // Ws <- W42_r
  __syncthreads();

  // ---- phase 7: C4b + epilogue ----
  mm_acc(cs, Ws, 64, nl0, f0, acc);  // + h4 @ W42_r
  {
    float bb[4] = {rb42.x, rb42.y, rb42.z, rb42.w};
#pragma unroll
    for (int j = 0; j < 4; j++) {
      int g = gb + nl0 + j;
      if (g < n) {
        float osc = rdv[j];
#pragma unroll
        for (int jj = 0; jj < 4; jj++) {
          int f = f0 + jj;
          float v = fmaxf(acc[j][jj] + bb[jj], 0.f);
          S2out[(size_t)g * 64 + f] = v;
          S2b[(size_t)g * 64 + f] = f2bf(v * osc);
        }
      }
    }
  }
}

// ---- phase-D quad MM: S1 = relu(S2@W2_0 + t1@W2_1 + t2@W2_2 + t3@W2_3 + b2); S1b = bf16 ----
__global__ __launch_bounds__(256, 4)
void k_mm_d(const float* __restrict__ S2, const unsigned short* __restrict__ t1b,
            const unsigned short* __restrict__ t2b, const unsigned short* __restrict__ t3b,
            const float* __restrict__ W2, const float* __restrict__ b2,
            float* __restrict__ S1, unsigned short* __restrict__ S1b, int n) {
  __shared__ float Ws[4096];
  __shared__ float as[64 * 68];
  const int tid = threadIdx.x;
  const int gb = blockIdx.x * 64;
  const int lane = tid & 63;
  const int fq = lane & 15, nq = lane >> 4;
  const int f0 = fq * 4;
  const int nl0 = (tid >> 6) * 16 + nq * 4;
  float acc[4][4];
  float4 sw0, sw1, sw2, sw3, sa0, sa1, sa2, sa3;
  float sc0, sc1, sc2, sc3;
  uint2 sb0, sb1, sb2, sb3;

  // prologue: stage0 (W2_0, S2 f32)
  WQ_ISSUE(W2);
  AQ_ISSUE_F32(S2, (const int*)nullptr);
  float4 rb2 = ((const float4*)b2)[fq];
  WQ_COMMIT();
  AQ_COMMIT_F32(as, false);
  __syncthreads();

  // phase 1: op0 (S2 f32)
  WQ_ISSUE(W2 + 4096);
  AQ_ISSUE_BF16(t1b);
  mm_zero(acc);
  mm_acc(as, Ws, 64, nl0, f0, acc);
  __syncthreads();
  WQ_COMMIT();
  AQ_COMMIT_BF16();
  __syncthreads();

  // phase 2: op1 (t1)
  WQ_ISSUE(W2 + 8192);
  AQ_ISSUE_BF16(t2b);
  mm_acc(as, Ws, 64, nl0, f0, acc);
  __syncthreads();
  WQ_COMMIT();
  AQ_COMMIT_BF16();
  __syncthreads();

  // phase 3: op2 (t2)
  WQ_ISSUE(W2 + 12288);
  AQ_ISSUE_BF16(t3b);
  mm_acc(as, Ws, 64, nl0, f0, acc);
  __syncthreads();
  WQ_COMMIT();
  AQ_COMMIT_BF16();
  __syncthreads();

  // phase 4: op3 (t3) + epilogue
  mm_acc(as, Ws, 64, nl0, f0, acc);
  {
    float bb[4] = {rb2.x, rb2.y, rb2.z, rb2.w};
#pragma unroll
    for (int j = 0; j < 4; j++) {
      int g = gb + nl0 + j;
      if (g < n) {
#pragma unroll
        for (int jj = 0; jj < 4; jj++) {
          int f = f0 + jj;
          float v = fmaxf(acc[j][jj] + bb[jj], 0.f);
          S1[(size_t)g * 64 + f] = v;
          S1b[(size_t)g * 64 + f] = f2bf(v);
        }
      }
    }
  }
}

// ---- phase-E FUSED: per-block gather of aggSS from S1b (bf16) + MM + final projection:
//      out = relu(aggSS'@W5_l + S1@W5_r + b5) @ Wl + bl ----
__global__ __launch_bounds__(256, 3)
void k_mm_e(const unsigned short* __restrict__ S1b16,
            const int* __restrict__ rs_ss, const int* __restrict__ cnt_ss,
            const int* __restrict__ srcs_ss,
            const float* __restrict__ W5_l, const float* __restrict__ S1,
            const float* __restrict__ W5_r, const float* __restrict__ b5,
            const float* __restrict__ Wl, const float* __restrict__ bl,
            float* __restrict__ out, int n) {
  __shared__ float Ws[4096];
  __shared__ float as[64 * 68];
  __shared__ float cs[64 * 68];
  const int tid = threadIdx.x;
  const int gb = blockIdx.x * 64;
  const int lane = tid & 63;
  const int fq = lane & 15, nq = lane >> 4;
  const int f0 = fq * 4;
  const int nl0 = (tid >> 6) * 16 + nq * 4;
  float acc[4][4];
  float4 sw0, sw1, sw2, sw3, sa0, sa1, sa2, sa3;
  float sc0, sc1, sc2, sc3;
  const unsigned* Xu = (const unsigned*)S1b16;
  const int q = lane & 31;
  const int h = lane >> 5;

  // prologue: stage0 (W5_r, S1) + projection scalars
  WQ_ISSUE(W5_r);
  AQ_ISSUE_F32(S1, (const int*)nullptr);
  float rwl0 = Wl[tid];
  float rwl1 = Wl[256 + tid];
  float4 rb5 = ((const float4*)b5)[fq];
  float rbl0 = bl[(2 * tid) & 7];
  float rbl1 = bl[(2 * tid + 1) & 7];
  WQ_COMMIT();                       // Ws <- W5_r
  AQ_COMMIT_F32(cs, false);          // cs <- S1

  // ---- gather aggSS' for our 64 rows from S1b (dual-half packed, scaled) -> as ----
  {
    const int w = tid >> 6;          // wave id 0..3
    for (int i = 0; i < 16; i++) {
      int r = w * 16 + i;
      int row = gb + r;
      float a0 = 0.f, a1 = 0.f, m = 1.f;
      if (row < n) {
        int rs = rs_ss[row], c = cnt_ss[row];
        m = 1.f / fmaxf((float)c, 1.f);
        int nh = (c - h + 1) >> 1;
        const int* sp = srcs_ss + rs + h;
        int k = 0;
        for (; k + 4 <= nh; k += 4) {
          int s0 = sp[2 * k], s1 = sp[2 * k + 2], s2 = sp[2 * k + 4], s3 = sp[2 * k + 6];
          unsigned r0 = Xu[(unsigned)s0 * 32 + q];
          unsigned r1 = Xu[(unsigned)s1 * 32 + q];
          unsigned r2 = Xu[(unsigned)s2 * 32 + q];
          unsigned r3 = Xu[(unsigned)s3 * 32 + q];
          a0 += (__uint_as_float(r0 << 16) + __uint_as_float(r1 << 16))
              + (__uint_as_float(r2 << 16) + __uint_as_float(r3 << 16));
          a1 += (__uint_as_float(r0 & 0xFFFF0000u) + __uint_as_float(r1 & 0xFFFF0000u))
              + (__uint_as_float(r2 & 0xFFFF0000u) + __uint_as_float(r3 & 0xFFFF0000u));
        }
        for (; k < nh; k++) {
          unsigned rr = Xu[(unsigned)sp[2 * k] * 32 + q];
          a0 += __uint_as_float(rr << 16);
          a1 += __uint_as_float(rr & 0xFFFF0000u);
        }
        a0 += __shfl_xor(a0, 32); a1 += __shfl_xor(a1, 32);
      }
      if (h == 0) *(float2*)(&as[r * 68 + 2 * q]) = make_float2(a0 * m, a1 * m);
    }
  }
  __syncthreads();

  // phase 1: S1 @ W5_r (W5_l issued, in flight under the MM)
  WQ_ISSUE(W5_l);
  mm_zero(acc);
  mm_acc(cs, Ws, 64, nl0, f0, acc);
  __syncthreads();
  WQ_COMMIT();                       // Ws <- W5_l
  __syncthreads();

  // phase 2: + aggSS' @ W5_l, then project
  mm_acc(as, Ws, 64, nl0, f0, acc);
  __syncthreads();
  {
    float bb[4] = {rb5.x, rb5.y, rb5.z, rb5.w};
#pragma unroll
    for (int j = 0; j < 4; j++)
#pragma unroll
      for (int jj = 0; jj < 4; jj++)
        as[(nl0 + j) * 68 + f0 + jj] = fmaxf(acc[j][jj] + bb[jj], 0.f);
  }
  Ws[tid] = rwl0;
  Ws[256 + tid] = rwl1;
  __syncthreads();
#pragma unroll
  for (int p = 0; p < 2; p++) {
    int idx = tid * 2 + p;
    int nl = idx >> 3, o = idx & 7;
    int g = gb + nl;
    if (g < n) {
      float a2 = (p == 0) ? rbl0 : rbl1;
#pragma unroll 8
      for (int k = 0; k < 64; k++) a2 += as[nl * 68 + k] * Ws[k * 8 + o];
      out[(size_t)g * 8 + o] = a2;
    }
  }
}

// ---------------- Host ----------------

extern "C" void kernel_launch(void* const* d_in, const int* in_sizes, int n_in,
                              void* d_out, int out_size, void* d_ws, size_t ws_size,
                              hipStream_t stream) {
  const float* game_x  = (const float*)d_in[0];
  const float* state_x = (const float*)d_in[1];
  const int*   ei_vv   = (const int*)d_in[2];
  const int*   et_vv   = (const int*)d_in[3];
  const int*   ei_h    = (const int*)d_in[4];
  const float* ew_h    = (const float*)d_in[5];
  const int*   ei_in   = (const int*)d_in[6];
  const int*   ei_ss   = (const int*)d_in[7];
  const float* W1_rel  = (const float*)d_in[8];
  const float* W1_root = (const float*)d_in[9];
  const float* b1      = (const float*)d_in[10];
  const float* W12     = (const float*)d_in[11];
  const float* b12     = (const float*)d_in[12];
  const float* W2      = (const float*)d_in[13];
  const float* b2      = (const float*)d_in[14];
  const float* W3_rel  = (const float*)d_in[15];
  const float* W3_root = (const float*)d_in[16];
  const float* b3      = (const float*)d_in[17];
  const float* W32_l   = (const float*)d_in[18];
  const float* W32_r   = (const float*)d_in[19];
  const float* b32     = (const float*)d_in[20];
  const float* W4_l    = (const float*)d_in[21];
  const float* W4_r    = (const float*)d_in[22];
  const float* b4      = (const float*)d_in[23];
  const float* W42_l   = (const float*)d_in[24];
  const float* W42_r   = (const float*)d_in[25];
  const float* b42     = (const float*)d_in[26];
  const float* W5_l    = (const float*)d_in[27];
  const float* W5_r    = (const float*)d_in[28];
  const float* b5      = (const float*)d_in[29];
  const float* Wl      = (const float*)d_in[30];
  const float* bl      = (const float*)d_in[31];

  // Workspace (4B slots), peak 26.05M slots = 104.2 MiB.
  float* ws = (float*)d_ws;
  int*   cnt_all = (int*)(ws + 0);              // 250K (vv|h|in|ss)
  int*   rs_all  = (int*)(ws + 250000);         // 250K (graph-local values)
  int*   bcnt    = (int*)(ws + 500000);         // 512
  int*   bbase   = (int*)(ws + 500512);         // 512
  int*   cb      = (int*)(ws + 501024);         // 512
  int*   srcs_ss = (int*)(ws + 760000);         // 0.8M  (lives through phase E)
  float4* x_pad  = (float4*)(ws + 1600000);     // 800K
  float4* h1p    = (float4*)(ws + 2400000);
  float4* h2p    = (float4*)(ws + 3200000);
  float4* h3p    = (float4*)(ws + 4000000);
  float4* ra4all = (float4*)(ws + 4800000);     // [NVV][5] float4 = 2.0M slots -> 6.8M
  float* dinvS   = ws + 6800000;                // 50K
  unsigned short* gx16 = (unsigned short*)(ws + 6850000);  // 3.2M slots -> 10.05M
  unsigned* temp_vv    = (unsigned*)(ws + 6850000);        // 1.6M, overlays gx16 front (dead before combine)
  float* aggHw = ws + 10050000;                 // 3.2M
  float* aggHu = ws + 13250000;                 // 3.2M
  float* aggIN = ws + 16450000;                 // 3.2M
  float* S1    = ws + 19650000;                 // 3.2M
  float* S2    = ws + 22850000;                 // 3.2M -> ends 26.05M
  // fill temps overlay agg regions (dead until phase B):
  uint2*    temp_h  = (uint2*)aggHw;
  unsigned* temp_in = (unsigned*)(aggHw + 1600000);
  unsigned* temp_ss = (unsigned*)(aggHw + 2400000);
  // overlays (dead-before-write verified in stream order):
  unsigned short* S2b = (unsigned short*)(ws + 4800000);     // in ra4all region (dead after combine_gx)
  unsigned short* u1b = (unsigned short*)(aggHw + 1600000);  // hop1 aux; aggHw dead after chainC
  unsigned short* t1b = (unsigned short*)aggHu;              // aggHu dead after chainC
  unsigned short* t2b = (unsigned short*)(aggHu + 1600000);
  unsigned short* t3b = (unsigned short*)aggIN;              // aggIN dead after chainC
  unsigned short* S1b = (unsigned short*)(aggIN + 1600000);  // k_mm_d shadow
  unsigned* payload_vv = (unsigned*)S1;                      // dead after phase A
  unsigned short* u2b  = (unsigned short*)S1;                // hop2 aux; S1 written later by k_mm_d
  int2*     eh         = (int2*)S2;                          // dead after aggB; S2 written by chainC
  int*      srcs_in    = (int*)(S2 + 1600000);

  const int* src_vv = ei_vv;  const int* dst_vv = ei_vv + E_VV;
  const int* src_h  = ei_h;   const int* dst_h  = ei_h + E_H;
  const int* src_in = ei_in;  const int* dst_in = ei_in + E_IN;
  const int* src_ss = ei_ss;  const int* dst_ss = ei_ss + E_SS;

  auto nblk = [](long long n) { return dim3((unsigned)((n + 255) / 256)); };
  const int NB64 = (NSV + 3) / 4;
  const int NB   = (NSV + 63) / 64;
  const int GC   = (ETOT + TC - 1) / TC;
  const int NBVV4 = (NVV + 63) / 64;   // 4 lanes/node vv kernels

  int* cnt_h  = cnt_all + H_ROW;
  int* cnt_in = cnt_all + IN_ROW;
  int* cnt_ss = cnt_all + SS_ROW;
  int* rs_vv  = rs_all;
  int* rs_h   = rs_all + H_ROW;
  int* rs_in  = rs_all + IN_ROW;
  int* rs_ss  = rs_all + SS_ROW;

  // ---- CSR build (fused) ----
  hipMemsetAsync(bcnt, 0, NBTOT * sizeof(int), stream);
  k_bucket_count<<<GC, 256, 0, stream>>>(dst_vv, dst_h, dst_in, dst_ss, bcnt);
  k_bucket_scan<<<1, 512, 0, stream>>>(bcnt, bbase, cb);
  k_fill_s1_all<<<SB1, 256, 0, stream>>>(src_vv, dst_vv, et_vv, src_h, dst_h, ew_h,
                                         src_in, dst_in, src_ss, dst_ss, cb,
                                         temp_vv, temp_h, temp_in, temp_ss);
  k_fill_s2_all<<<NBTOT, 256, 0, stream>>>(temp_vv, temp_h, temp_in, temp_ss, bbase,
                                           payload_vv, eh, srcs_in, srcs_ss,
                                           rs_all, cnt_all, game_x, x_pad, dinvS);

  // ---- Phase A: v-graph 5-dim (4 lanes/node) ----
  k_vv_pass1<<<NBVV4, 256, 0, stream>>>(x_pad, rs_vv, cnt_all, payload_vv, ra4all, h1p);
  k_vv_hop<<<NBVV4, 256, 0, stream>>>(h1p, rs_vv, cnt_all, payload_vv, h2p);
  k_vv_hop<<<NBVV4, 256, 0, stream>>>(h2p, rs_vv, cnt_all, payload_vv, h3p);
  k_combine_gx<<<dim3((NVV + 31) / 32), 256, 0, stream>>>(x_pad, ra4all, h1p, h2p, h3p,
                                                          W1_rel, W1_root, b1, W12, b12, gx16);

  // ---- Phase B: fused 64-dim bf16 gathers ----
  k_aggB<<<2 * NB64, 256, 0, stream>>>(gx16, rs_h, cnt_h, eh, rs_in, cnt_in, srcs_in,
                                       aggHw, aggHu, aggIN, NB64);

  // ---- Phase C: fused 4-MM chain -> S2 (+ dinv-prescaled bf16 shadow) ----
  k_mm_chainC<<<NB, 256, 0, stream>>>(aggHw, state_x, aggHu, cnt_h, aggIN, cnt_in,
                                      W3_rel, W3_root, b3, W32_l, W32_r, b32,
                                      W4_l, W4_r, b4, W42_l, W42_r, b42,
                                      S2, S2b, dinvS, NSV);

  // ---- Phase D: TAG on s-s (prescaled bf16 hops) + fused quad MM ----
  k_tag64b<<<NB64, 256, 0, stream>>>(S2b, rs_ss, cnt_ss, srcs_ss, dinvS, t1b, u1b, NSV);
  k_tag64b<<<NB64, 256, 0, stream>>>(u1b, rs_ss, cnt_ss, srcs_ss, dinvS, t2b, u2b, NSV);
  k_tag64b<<<NB64, 256, 0, stream>>>(u2b, rs_ss, cnt_ss, srcs_ss, dinvS, t3b, nullptr, NSV);
  k_mm_d<<<NB, 256, 0, stream>>>(S2, t1b, t2b, t3b, W2, b2, S1, S1b, NSV);

  // ---- Phase E: fused SAGE gather + MM + final projection ----
  k_mm_e<<<NB, 256, 0, stream>>>(S1b, rs_ss, cnt_ss, srcs_ss,
                                 W5_l, S1, W5_r, b5, Wl, bl, (float*)d_out, NSV);
}

// Round 8
// 597.160 us; speedup vs baseline: 1.0869x; 1.0869x over previous
//
#include <hip/hip_runtime.h>

#define NVV 100000
#define NSV 50000
#define E_VV 1600000
#define E_H  800000
#define E_IN 800000
#define E_SS 800000
#define ETOT 4000000
#define DIN 5
#define H_ROW 100000          // concatenated cnt/rs space: vv|h|in|ss
#define IN_ROW 150000
#define SS_ROW 200000
#define NROWS 250000
#define POS_H  E_VV
#define POS_IN (E_VV + E_H)
#define POS_SS (E_VV + E_H + E_IN)
#define NBUK 196              // vv buckets (dst >> 9)
#define NBUKS 98              // NSV-graph buckets
#define NBTOT 490             // vv|h|in|ss bucket space
#define BUK_H  196
#define BUK_IN 294
#define BUK_SS 392
#define BSHIFT 9
#define T1 4096               // edges per fill-stage-1 block
#define TC 16384              // edges per bucket-count block
#define G1VV 391              // ceil(E_VV/T1)
#define G1S  196              // ceil(E_H/T1)
#define SB1  (G1VV + 3 * G1S) // 979 fused stage-1 blocks

__device__ __forceinline__ unsigned short f2bf(float x) {
  unsigned b = __float_as_uint(x);
  return (unsigned short)((b + 0x7FFFu + ((b >> 16) & 1u)) >> 16);
}
__device__ __forceinline__ float bf2f(unsigned short u) {
  return __uint_as_float(((unsigned)u) << 16);
}
#define BFLO(u) __uint_as_float((u) << 16)
#define BFHI(u) __uint_as_float((u) & 0xFFFF0000u)

// ====================== CSR build: bucket counts -> bases -> fused binned fills ======================

__global__ __launch_bounds__(256)
void k_bucket_count(const int* __restrict__ d_vv, const int* __restrict__ d_h,
                    const int* __restrict__ d_in, const int* __restrict__ d_ss,
                    int* __restrict__ bcnt) {
  __shared__ int h[NBTOT];
  const int tid = threadIdx.x;
  for (int i = tid; i < NBTOT; i += 256) h[i] = 0;
  __syncthreads();
  const int base = blockIdx.x * TC;
#pragma unroll 4
  for (int k = 0; k < TC / 256; k++) {
    int e = base + k * 256 + tid;
    int bi = -1;
    if (e < E_VV) bi = d_vv[e] >> BSHIFT;
    else if (e < POS_IN) bi = BUK_H + (d_h[e - POS_H] >> BSHIFT);
    else if (e < POS_SS) bi = BUK_IN + (d_in[e - POS_IN] >> BSHIFT);
    else if (e < ETOT) bi = BUK_SS + (d_ss[e - POS_SS] >> BSHIFT);
    if (bi >= 0) atomicAdd(&h[bi], 1);
  }
  __syncthreads();
  for (int i = tid; i < NBTOT; i += 256) if (h[i]) atomicAdd(&bcnt[i], h[i]);
}

__global__ __launch_bounds__(512)
void k_bucket_scan(const int* __restrict__ bcnt, int* __restrict__ bbase, int* __restrict__ cb) {
  __shared__ int sd[512];
  int t = threadIdx.x;
  int v = (t < NBTOT) ? bcnt[t] : 0;
  sd[t] = v; __syncthreads();
  for (int off = 1; off < 512; off <<= 1) {
    int x = (t >= off) ? sd[t - off] : 0;
    __syncthreads();
    sd[t] += x;
    __syncthreads();
  }
  int segstart = (t < BUK_H) ? 0 : (t < BUK_IN) ? BUK_H : (t < BUK_SS) ? BUK_IN : BUK_SS;
  int excl = ((t > 0) ? sd[t - 1] : 0) - ((segstart > 0) ? sd[segstart - 1] : 0);
  if (t < NBTOT) { bbase[t] = excl; cb[t] = excl; }
}

// ---- fused stage 1: all 4 graphs, bucket-grouped binning, coalesced run writes ----
__global__ __launch_bounds__(256)
void k_fill_s1_all(const int* __restrict__ s_vv, const int* __restrict__ d_vv,
                   const int* __restrict__ et,
                   const int* __restrict__ s_h, const int* __restrict__ d_h,
                   const float* __restrict__ ew,
                   const int* __restrict__ s_in, const int* __restrict__ d_in,
                   const int* __restrict__ s_ss, const int* __restrict__ d_ss,
                   int* __restrict__ cb,
                   unsigned* __restrict__ temp_vv, uint2* __restrict__ temp_h,
                   unsigned* __restrict__ temp_in, unsigned* __restrict__ temp_ss) {
  __shared__ int hist[NBUK], lbase[NBUK], run[NBUK], gb[NBUK];
  __shared__ int sc[256];
  __shared__ unsigned stage[T1];
  __shared__ unsigned stageW[T1];
  __shared__ int gpos[T1];
  const int tid = threadIdx.x;
  const int b = blockIdx.x;
  int g, tile;
  if (b < G1VV) { g = 0; tile = b; }
  else if (b < G1VV + G1S) { g = 1; tile = b - G1VV; }
  else if (b < G1VV + 2 * G1S) { g = 2; tile = b - G1VV - G1S; }
  else { g = 3; tile = b - G1VV - 2 * G1S; }
  const int ne = (g == 0) ? E_VV : E_H;
  const int nbuk = (g == 0) ? NBUK : NBUKS;
  const int cboff = (g == 0) ? 0 : (g == 1) ? BUK_H : (g == 2) ? BUK_IN : BUK_SS;
  const int* S = (g == 0) ? s_vv : (g == 1) ? s_h : (g == 2) ? s_in : s_ss;
  const int* D = (g == 0) ? d_vv : (g == 1) ? d_h : (g == 2) ? d_in : d_ss;
  const int base = tile * T1;
  const int nvalid = min(T1, ne - base);
  for (int i = tid; i < nbuk; i += 256) { hist[i] = 0; run[i] = 0; }
  __syncthreads();
  int dv[16]; unsigned pk[16], pkw[16];
#pragma unroll
  for (int k = 0; k < 16; k++) {
    int e = base + k * 256 + tid;
    if (e - base < nvalid) {
      int d = D[e];
      dv[k] = d;
      if (g == 0) pk[k] = (unsigned)(((d & 511) << 19) | (et[e] << 17) | S[e]);
      else pk[k] = (unsigned)(((d & 511) << 17) | S[e]);
      if (g == 1) pkw[k] = (unsigned)__float_as_int(ew[e]);
      atomicAdd(&hist[d >> BSHIFT], 1);
    } else dv[k] = -1;
  }
  __syncthreads();
  int my = (tid < nbuk) ? hist[tid] : 0;
  sc[tid] = my; __syncthreads();
  for (int off = 1; off < 256; off <<= 1) {
    int t = (tid >= off) ? sc[tid - off] : 0;
    __syncthreads();
    sc[tid] += t;
    __syncthreads();
  }
  if (tid < nbuk) {
    lbase[tid] = sc[tid] - my;
    gb[tid] = my ? atomicAdd(&cb[cboff + tid], my) : 0;
  }
  __syncthreads();
#pragma unroll
  for (int k = 0; k < 16; k++) {
    if (dv[k] >= 0) {
      int bu = dv[k] >> BSHIFT;
      int loc = atomicAdd(&run[bu], 1);
      int li = lbase[bu] + loc;
      stage[li] = pk[k];
      if (g == 1) stageW[li] = pkw[k];
      gpos[li] = gb[bu] + loc;
    }
  }
  __syncthreads();
  if (g == 0)      for (int i = tid; i < nvalid; i += 256) temp_vv[gpos[i]] = stage[i];
  else if (g == 1) for (int i = tid; i < nvalid; i += 256) temp_h[gpos[i]] = make_uint2(stage[i], stageW[i]);
  else if (g == 2) for (int i = tid; i < nvalid; i += 256) temp_in[gpos[i]] = stage[i];
  else             for (int i = tid; i < nvalid; i += 256) temp_ss[gpos[i]] = stage[i];
}

// ---- fused stage 2 ----
__global__ __launch_bounds__(256)
void k_fill_s2_all(const unsigned* __restrict__ temp_vv, const uint2* __restrict__ temp_h,
                   const unsigned* __restrict__ temp_in, const unsigned* __restrict__ temp_ss,
                   const int* __restrict__ bbase,
                   unsigned* __restrict__ payload_vv, int2* __restrict__ eh,
                   int* __restrict__ srcs_in, int* __restrict__ srcs_ss,
                   int* __restrict__ rs_all, int* __restrict__ cnt_all,
                   const float* __restrict__ x, float4* __restrict__ xp,
                   float* __restrict__ dinvS) {
  __shared__ int lcnt[512], lpos[512];
  __shared__ int sc[256];
  const int b = blockIdx.x, tid = threadIdx.x;
  int g, lb;
  if (b < BUK_H) { g = 0; lb = b; }
  else if (b < BUK_IN) { g = 1; lb = b - BUK_H; }
  else if (b < BUK_SS) { g = 2; lb = b - BUK_IN; }
  else { g = 3; lb = b - BUK_SS; }
  const int d0 = lb << BSHIFT;
  const int nrows = (g == 0) ? NVV : NSV;
  const int rowbase = (g == 0) ? 0 : (g == 1) ? H_ROW : (g == 2) ? IN_ROW : SS_ROW;
  const int ne = (g == 0) ? E_VV : E_H;
  const int lastb = (g == 0) ? NBUK - 1 : NBUKS - 1;
  const int shift = (g == 0) ? 19 : 17;
  lcnt[tid] = 0; lcnt[tid + 256] = 0;
  __syncthreads();
  const int gstart = bbase[b];
  const int gend = (lb == lastb) ? ne : bbase[b + 1];
  if (g == 1) {
    for (int i = gstart + tid; i < gend; i += 256) atomicAdd(&lcnt[temp_h[i].x >> 17], 1);
  } else {
    const unsigned* tp = (g == 0) ? temp_vv : (g == 2) ? temp_in : temp_ss;
    for (int i = gstart + tid; i < gend; i += 256) atomicAdd(&lcnt[tp[i] >> shift], 1);
  }
  __syncthreads();
  int c0 = lcnt[2 * tid], c1 = lcnt[2 * tid + 1];
  int ps = c0 + c1;
  sc[tid] = ps; __syncthreads();
  for (int off = 1; off < 256; off <<= 1) {
    int x2 = (tid >= off) ? sc[tid - off] : 0;
    __syncthreads();
    sc[tid] += x2;
    __syncthreads();
  }
  int basep = gstart + sc[tid] - ps;
  lpos[2 * tid] = basep;
  lpos[2 * tid + 1] = basep + c0;
  __syncthreads();
  for (int d = tid; d < 512; d += 256) {
    int gd = d0 + d;
    if (gd < nrows) {
      rs_all[rowbase + gd] = lpos[d];
      cnt_all[rowbase + gd] = lcnt[d];
      if (g == 0) {
        float dc = (float)lcnt[d];
        float di = dc > 0.f ? rsqrtf(dc) : 0.f;
        const float* xr = x + (size_t)gd * 5;
        xp[gd * 2]     = make_float4(xr[0], xr[1], xr[2], xr[3]);
        xp[gd * 2 + 1] = make_float4(xr[4], di, 0.f, 0.f);
      } else if (g == 3) {
        float dc = (float)lcnt[d];
        dinvS[gd] = dc > 0.f ? rsqrtf(dc) : 0.f;
      }
    }
  }
  __syncthreads();
  if (g == 0) {
    for (int i = gstart + tid; i < gend; i += 256) {
      unsigned en = temp_vv[i];
      int pos = atomicAdd(&lpos[en >> 19], 1);
      payload_vv[pos] = en & 0x7FFFFu;
    }
  } else if (g == 1) {
    for (int i = gstart + tid; i < gend; i += 256) {
      uint2 en = temp_h[i];
      int pos = atomicAdd(&lpos[en.x >> 17], 1);
      eh[pos] = make_int2((int)(en.x & 0x1FFFFu), (int)en.y);
    }
  } else if (g == 2) {
    for (int i = gstart + tid; i < gend; i += 256) {
      unsigned en = temp_in[i];
      int pos = atomicAdd(&lpos[en >> 17], 1);
      srcs_in[pos] = (int)(en & 0x1FFFFu);
    }
  } else {
    for (int i = gstart + tid; i < gend; i += 256) {
      unsigned en = temp_ss[i];
      int pos = atomicAdd(&lpos[en >> 17], 1);
      srcs_ss[pos] = (int)(en & 0x1FFFFu);
    }
  }
}

// ====================== Phase A: v-graph (5-dim, padded rows, 4 lanes/node) ======================

__global__ __launch_bounds__(256)
void k_vv_pass1(const float4* __restrict__ xp,
                const int* __restrict__ rowstart, const int* __restrict__ cnt,
                const unsigned* __restrict__ payload,
                float4* __restrict__ ra4all, float4* __restrict__ h1p) {
  const int tid = threadIdx.x;
  const int d = blockIdx.x * 64 + (tid >> 2);
  if (d >= NVV) return;
  const int q = tid & 3;
  int rs = rowstart[d], c = cnt[d];
  float a0[5] = {0,0,0,0,0}, a1[5] = {0,0,0,0,0}, a2[5] = {0,0,0,0,0}, h[5] = {0,0,0,0,0};
  float c0 = 0.f, c1 = 0.f, c2 = 0.f;
  int j = q;
  for (; j + 4 < c; j += 8) {
    unsigned pA = payload[rs + j], pB = payload[rs + j + 4];
    int sA = pA & 0x1FFFF, rA = pA >> 17;
    int sB = pB & 0x1FFFF, rB = pB >> 17;
    float4 xA0 = xp[sA * 2], xA1 = xp[sA * 2 + 1];
    float4 xB0 = xp[sB * 2], xB1 = xp[sB * 2 + 1];
    float xsA[5] = {xA0.x, xA0.y, xA0.z, xA0.w, xA1.x};
    float xsB[5] = {xB0.x, xB0.y, xB0.z, xB0.w, xB1.x};
    float wA = xA1.y, wB = xB1.y;
    float mA0 = (rA == 0) ? 1.f : 0.f, mA1 = (rA == 1) ? 1.f : 0.f, mA2 = (rA == 2) ? 1.f : 0.f;
    float mB0 = (rB == 0) ? 1.f : 0.f, mB1 = (rB == 1) ? 1.f : 0.f, mB2 = (rB == 2) ? 1.f : 0.f;
    c0 += mA0 + mB0; c1 += mA1 + mB1; c2 += mA2 + mB2;
#pragma unroll
    for (int k = 0; k < 5; k++) {
      h[k] += wA * xsA[k] + wB * xsB[k];
      a0[k] += mA0 * xsA[k] + mB0 * xsB[k];
      a1[k] += mA1 * xsA[k] + mB1 * xsB[k];
      a2[k] += mA2 * xsA[k] + mB2 * xsB[k];
    }
  }
  for (; j < c; j += 4) {
    unsigned p = payload[rs + j];
    int s = p & 0x1FFFF, r = p >> 17;
    float4 x0 = xp[s * 2], x1 = xp[s * 2 + 1];
    float xs[5] = {x0.x, x0.y, x0.z, x0.w, x1.x};
    float wsc = x1.y;
    float m0 = (r == 0) ? 1.f : 0.f, m1 = (r == 1) ? 1.f : 0.f, m2 = (r == 2) ? 1.f : 0.f;
    c0 += m0; c1 += m1; c2 += m2;
#pragma unroll
    for (int k = 0; k < 5; k++) {
      h[k] += wsc * xs[k];
      a0[k] += m0 * xs[k]; a1[k] += m1 * xs[k]; a2[k] += m2 * xs[k];
    }
  }
  // quad butterfly reduce: every lane ends with the full sums
#pragma unroll
  for (int k = 0; k < 5; k++) {
    a0[k] += __shfl_xor(a0[k], 1); a0[k] += __shfl_xor(a0[k], 2);
    a1[k] += __shfl_xor(a1[k], 1); a1[k] += __shfl_xor(a1[k], 2);
    a2[k] += __shfl_xor(a2[k], 1); a2[k] += __shfl_xor(a2[k], 2);
    h[k]  += __shfl_xor(h[k], 1);  h[k]  += __shfl_xor(h[k], 2);
  }
  c0 += __shfl_xor(c0, 1); c0 += __shfl_xor(c0, 2);
  c1 += __shfl_xor(c1, 1); c1 += __shfl_xor(c1, 2);
  c2 += __shfl_xor(c2, 1); c2 += __shfl_xor(c2, 2);
  float dv = xp[d * 2 + 1].y;
  float4* ra4 = ra4all + d * 5;
  if (q == 0) {
    ra4[0] = make_float4(a0[0], a0[1], a0[2], a0[3]);
    ra4[1] = make_float4(a0[4], a1[0], a1[1], a1[2]);
  } else if (q == 1) {
    ra4[2] = make_float4(a1[3], a1[4], a2[0], a2[1]);
    ra4[3] = make_float4(a2[2], a2[3], a2[4], c0);
  } else if (q == 2) {
    ra4[4] = make_float4(c1, c2, 0.f, 0.f);
  } else {
    h1p[d * 2]     = make_float4(dv * h[0], dv * h[1], dv * h[2], dv * h[3]);
    h1p[d * 2 + 1] = make_float4(dv * h[4], dv, 0.f, 0.f);
  }
}

__global__ __launch_bounds__(256)
void k_vv_hop(const float4* __restrict__ hinp,
              const int* __restrict__ rowstart, const int* __restrict__ cnt,
              const unsigned* __restrict__ payload, float4* __restrict__ houtp) {
  const int tid = threadIdx.x;
  const int d = blockIdx.x * 64 + (tid >> 2);
  if (d >= NVV) return;
  const int q = tid & 3;
  int rs = rowstart[d], c = cnt[d];
  float h[5] = {0,0,0,0,0};
  int j = q;
  for (; j + 4 < c; j += 8) {
    unsigned p0 = payload[rs + j], p1 = payload[rs + j + 4];
    int s0 = p0 & 0x1FFFF, s1 = p1 & 0x1FFFF;
    float4 a0 = hinp[s0 * 2], b0 = hinp[s0 * 2 + 1];
    float4 a1 = hinp[s1 * 2], b1 = hinp[s1 * 2 + 1];
    float w0 = b0.y, w1 = b1.y;
    h[0] += w0 * a0.x + w1 * a1.x;
    h[1] += w0 * a0.y + w1 * a1.y;
    h[2] += w0 * a0.z + w1 * a1.z;
    h[3] += w0 * a0.w + w1 * a1.w;
    h[4] += w0 * b0.x + w1 * b1.x;
  }
  for (; j < c; j += 4) {
    int s = payload[rs + j] & 0x1FFFF;
    float4 x0 = hinp[s * 2], x1 = hinp[s * 2 + 1];
    float wsc = x1.y;
    h[0] += wsc * x0.x; h[1] += wsc * x0.y; h[2] += wsc * x0.z; h[3] += wsc * x0.w;
    h[4] += wsc * x1.x;
  }
#pragma unroll
  for (int k = 0; k < 5; k++) {
    h[k] += __shfl_xor(h[k], 1);
    h[k] += __shfl_xor(h[k], 2);
  }
  float dv = hinp[d * 2 + 1].y;
  if (q == 0)      houtp[d * 2]     = make_float4(dv * h[0], dv * h[1], dv * h[2], dv * h[3]);
  else if (q == 1) houtp[d * 2 + 1] = make_float4(dv * h[4], dv, 0.f, 0.f);
}

// 8 nodes/thread, Ws column in 35 VGPRs, float4 relall loads.
__global__ __launch_bounds__(256)
void k_combine_gx(const float4* __restrict__ xp,
                  const float4* __restrict__ ra4all,
                  const float4* __restrict__ h1p, const float4* __restrict__ h2p,
                  const float4* __restrict__ h3p,
                  const float* __restrict__ W1_rel, const float* __restrict__ W1_root,
                  const float* __restrict__ b1,
                  const float* __restrict__ W12, const float* __restrict__ b12,
                  unsigned short* __restrict__ gx16) {
  __shared__ float Ws[7 * 320];
  __shared__ float bs[64];
  int tid = threadIdx.x;
  for (int i = tid; i < 320; i += 256) {
    Ws[i]        = W1_root[i] + W12[i];
    Ws[320 + i]  = W1_rel[i];
    Ws[640 + i]  = W1_rel[320 + i];
    Ws[960 + i]  = W1_rel[640 + i];
    Ws[1280 + i] = W12[320 + i];
    Ws[1600 + i] = W12[640 + i];
    Ws[1920 + i] = W12[960 + i];
  }
  if (tid < 64) bs[tid] = b1[tid] + b12[tid];
  __syncthreads();
  const int f = tid & 63;
  const int grp = tid >> 6;
  float wcol[35];
#pragma unroll
  for (int t = 0; t < 35; t++) wcol[t] = Ws[t * 64 + f];
  const float bias = bs[f];
  const int v0 = blockIdx.x * 32 + grp * 8;
  for (int n = 0; n < 8; n++) {
    int v = v0 + n;
    if (v >= NVV) return;
    float in[35];
    {
      float4 x0 = xp[v * 2], x1 = xp[v * 2 + 1];
      in[0] = x0.x; in[1] = x0.y; in[2] = x0.z; in[3] = x0.w; in[4] = x1.x;
    }
    {
      const float4* ra = ra4all + v * 5;
      float4 r0 = ra[0], r1 = ra[1], r2 = ra[2], r3 = ra[3], r4 = ra[4];
      float i0 = 1.0f / fmaxf(r3.w, 1.0f);
      float i1 = 1.0f / fmaxf(r4.x, 1.0f);
      float i2 = 1.0f / fmaxf(r4.y, 1.0f);
      in[5]  = r0.x * i0; in[6]  = r0.y * i0; in[7]  = r0.z * i0; in[8]  = r0.w * i0; in[9]  = r1.x * i0;
      in[10] = r1.y * i1; in[11] = r1.z * i1; in[12] = r1.w * i1; in[13] = r2.x * i1; in[14] = r2.y * i1;
      in[15] = r2.z * i2; in[16] = r2.w * i2; in[17] = r3.x * i2; in[18] = r3.y * i2; in[19] = r3.z * i2;
    }
    {
      float4 a = h1p[v * 2], b = h1p[v * 2 + 1];
      in[20] = a.x; in[21] = a.y; in[22] = a.z; in[23] = a.w; in[24] = b.x;
      a = h2p[v * 2]; b = h2p[v * 2 + 1];
      in[25] = a.x; in[26] = a.y; in[27] = a.z; in[28] = a.w; in[29] = b.x;
      a = h3p[v * 2]; b = h3p[v * 2 + 1];
      in[30] = a.x; in[31] = a.y; in[32] = a.z; in[33] = a.w; in[34] = b.x;
    }
    float acc = bias;
#pragma unroll
    for (int t = 0; t < 35; t++) acc += in[t] * wcol[t];
    gx16[v * 64 + f] = f2bf(acc);
  }
}

// ================= 64-dim CSR gathers (R8 quad-slot: 4 edges / wave-load, 8 B/lane) =================
// lane = (h in 0..3 edge slot, q in 0..15 feature group); lane q holds features 4q..4q+3
// as uint2; slot h walks edges j ≡ h (mod 4). One wave load = 4 rows (512 B).
// Reduce: shfl_xor 16 + 32; h==0 lanes (0..15) write float4 / packed uint2.

__global__ __launch_bounds__(256)
void k_aggB(const unsigned short* __restrict__ X16,
            const int* __restrict__ rs_h, const int* __restrict__ cnt_h,
            const int2* __restrict__ eh,
            const int* __restrict__ rs_in, const int* __restrict__ cnt_in,
            const int* __restrict__ srcs_in,
            float* __restrict__ outw, float* __restrict__ outu, float* __restrict__ outIN,
            int nb64) {
  const uint2* X2 = (const uint2*)X16;
  int bb = blockIdx.x;
  int lane = threadIdx.x & 63;
  int q = lane & 15;
  int h = lane >> 4;
  if (bb < nb64) {
    int wid = bb * 4 + (threadIdx.x >> 6);
    if (wid >= NSV) return;
    int rs = rs_h[wid], c = cnt_h[wid];
    int nh = (c - h + 3) >> 2;
    const int2* ep = eh + rs + h;
    float au0 = 0.f, au1 = 0.f, au2 = 0.f, au3 = 0.f;
    float aw0 = 0.f, aw1 = 0.f, aw2 = 0.f, aw3 = 0.f;
    int k = 0;
    for (; k + 2 <= nh; k += 2) {
      int2 p0 = ep[4 * k], p1 = ep[4 * k + 4];
      uint2 r0 = X2[(unsigned)p0.x * 16 + q];
      uint2 r1 = X2[(unsigned)p1.x * 16 + q];
      float w0 = __int_as_float(p0.y), w1 = __int_as_float(p1.y);
      float v00 = BFLO(r0.x), v01 = BFHI(r0.x), v02 = BFLO(r0.y), v03 = BFHI(r0.y);
      float v10 = BFLO(r1.x), v11 = BFHI(r1.x), v12 = BFLO(r1.y), v13 = BFHI(r1.y);
      au0 += v00 + v10; au1 += v01 + v11; au2 += v02 + v12; au3 += v03 + v13;
      aw0 += w0 * v00 + w1 * v10; aw1 += w0 * v01 + w1 * v11;
      aw2 += w0 * v02 + w1 * v12; aw3 += w0 * v03 + w1 * v13;
    }
    for (; k < nh; k++) {
      int2 p = ep[4 * k];
      uint2 r = X2[(unsigned)p.x * 16 + q];
      float w = __int_as_float(p.y);
      float v0 = BFLO(r.x), v1 = BFHI(r.x), v2 = BFLO(r.y), v3 = BFHI(r.y);
      au0 += v0; au1 += v1; au2 += v2; au3 += v3;
      aw0 += w * v0; aw1 += w * v1; aw2 += w * v2; aw3 += w * v3;
    }
    au0 += __shfl_xor(au0, 16); au0 += __shfl_xor(au0, 32);
    au1 += __shfl_xor(au1, 16); au1 += __shfl_xor(au1, 32);
    au2 += __shfl_xor(au2, 16); au2 += __shfl_xor(au2, 32);
    au3 += __shfl_xor(au3, 16); au3 += __shfl_xor(au3, 32);
    aw0 += __shfl_xor(aw0, 16); aw0 += __shfl_xor(aw0, 32);
    aw1 += __shfl_xor(aw1, 16); aw1 += __shfl_xor(aw1, 32);
    aw2 += __shfl_xor(aw2, 16); aw2 += __shfl_xor(aw2, 32);
    aw3 += __shfl_xor(aw3, 16); aw3 += __shfl_xor(aw3, 32);
    if (h == 0) {
      ((float4*)outw)[wid * 16 + q] = make_float4(aw0, aw1, aw2, aw3);
      ((float4*)outu)[wid * 16 + q] = make_float4(au0, au1, au2, au3);
    }
  } else {
    int wid = (bb - nb64) * 4 + (threadIdx.x >> 6);
    if (wid >= NSV) return;
    int rs = rs_in[wid], c = cnt_in[wid];
    int nh = (c - h + 3) >> 2;
    const int* sp = srcs_in + rs + h;
    float a0 = 0.f, a1 = 0.f, a2 = 0.f, a3 = 0.f;
    int k = 0;
    for (; k + 2 <= nh; k += 2) {
      int s0 = sp[4 * k], s1 = sp[4 * k + 4];
      uint2 r0 = X2[(unsigned)s0 * 16 + q];
      uint2 r1 = X2[(unsigned)s1 * 16 + q];
      a0 += BFLO(r0.x) + BFLO(r1.x); a1 += BFHI(r0.x) + BFHI(r1.x);
      a2 += BFLO(r0.y) + BFLO(r1.y); a3 += BFHI(r0.y) + BFHI(r1.y);
    }
    for (; k < nh; k++) {
      uint2 r = X2[(unsigned)sp[4 * k] * 16 + q];
      a0 += BFLO(r.x); a1 += BFHI(r.x); a2 += BFLO(r.y); a3 += BFHI(r.y);
    }
    a0 += __shfl_xor(a0, 16); a0 += __shfl_xor(a0, 32);
    a1 += __shfl_xor(a1, 16); a1 += __shfl_xor(a1, 32);
    a2 += __shfl_xor(a2, 16); a2 += __shfl_xor(a2, 32);
    a3 += __shfl_xor(a3, 16); a3 += __shfl_xor(a3, 32);
    if (h == 0) ((float4*)outIN)[wid * 16 + q] = make_float4(a0, a1, a2, a3);
  }
}

__global__ __launch_bounds__(256)
void k_agg64b(const unsigned short* __restrict__ X16,
              const int* __restrict__ rowstart, const int* __restrict__ cnt,
              const int* __restrict__ srcs, float* __restrict__ out, int n) {
  const uint2* X2 = (const uint2*)X16;
  int wid = blockIdx.x * 4 + (threadIdx.x >> 6);
  if (wid >= n) return;
  int lane = threadIdx.x & 63;
  int q = lane & 15;
  int h = lane >> 4;
  int rs = rowstart[wid], c = cnt[wid];
  int nh = (c - h + 3) >> 2;
  const int* sp = srcs + rs + h;
  float a0 = 0.f, a1 = 0.f, a2 = 0.f, a3 = 0.f;
  int k = 0;
  for (; k + 2 <= nh; k += 2) {
    int s0 = sp[4 * k], s1 = sp[4 * k + 4];
    uint2 r0 = X2[(unsigned)s0 * 16 + q];
    uint2 r1 = X2[(unsigned)s1 * 16 + q];
    a0 += BFLO(r0.x) + BFLO(r1.x); a1 += BFHI(r0.x) + BFHI(r1.x);
    a2 += BFLO(r0.y) + BFLO(r1.y); a3 += BFHI(r0.y) + BFHI(r1.y);
  }
  for (; k < nh; k++) {
    uint2 r = X2[(unsigned)sp[4 * k] * 16 + q];
    a0 += BFLO(r.x); a1 += BFHI(r.x); a2 += BFLO(r.y); a3 += BFHI(r.y);
  }
  a0 += __shfl_xor(a0, 16); a0 += __shfl_xor(a0, 32);
  a1 += __shfl_xor(a1, 16); a1 += __shfl_xor(a1, 32);
  a2 += __shfl_xor(a2, 16); a2 += __shfl_xor(a2, 32);
  a3 += __shfl_xor(a3, 16); a3 += __shfl_xor(a3, 32);
  if (h == 0) ((float4*)out)[wid * 16 + q] = make_float4(a0, a1, a2, a3);
}

// prescaled TAG hop: U = dinv ⊙ t (bf16). t_out = dinv[d]*Σ U[s]; u_out = dinv[d]*t_out.
__global__ __launch_bounds__(256)
void k_tag64b(const unsigned short* __restrict__ U16,
              const int* __restrict__ rowstart, const int* __restrict__ cnt,
              const int* __restrict__ srcs, const float* __restrict__ dinv,
              unsigned short* __restrict__ t_out, unsigned short* __restrict__ u_out, int n) {
  const uint2* X2 = (const uint2*)U16;
  int wid = blockIdx.x * 4 + (threadIdx.x >> 6);
  if (wid >= n) return;
  int lane = threadIdx.x & 63;
  int q = lane & 15;
  int h = lane >> 4;
  int rs = rowstart[wid], c = cnt[wid];
  int nh = (c - h + 3) >> 2;
  const int* sp = srcs + rs + h;
  float a0 = 0.f, a1 = 0.f, a2 = 0.f, a3 = 0.f;
  int k = 0;
  for (; k + 2 <= nh; k += 2) {
    int s0 = sp[4 * k], s1 = sp[4 * k + 4];
    uint2 r0 = X2[(unsigned)s0 * 16 + q];
    uint2 r1 = X2[(unsigned)s1 * 16 + q];
    a0 += BFLO(r0.x) + BFLO(r1.x); a1 += BFHI(r0.x) + BFHI(r1.x);
    a2 += BFLO(r0.y) + BFLO(r1.y); a3 += BFHI(r0.y) + BFHI(r1.y);
  }
  for (; k < nh; k++) {
    uint2 r = X2[(unsigned)sp[4 * k] * 16 + q];
    a0 += BFLO(r.x); a1 += BFHI(r.x); a2 += BFLO(r.y); a3 += BFHI(r.y);
  }
  a0 += __shfl_xor(a0, 16); a0 += __shfl_xor(a0, 32);
  a1 += __shfl_xor(a1, 16); a1 += __shfl_xor(a1, 32);
  a2 += __shfl_xor(a2, 16); a2 += __shfl_xor(a2, 32);
  a3 += __shfl_xor(a3, 16); a3 += __shfl_xor(a3, 32);
  if (h == 0) {
    float dv = dinv[wid];
    float t0 = dv * a0, t1 = dv * a1, t2 = dv * a2, t3 = dv * a3;
    ((uint2*)t_out)[wid * 16 + q] =
        make_uint2((unsigned)f2bf(t0) | ((unsigned)f2bf(t1) << 16),
                   (unsigned)f2bf(t2) | ((unsigned)f2bf(t3) << 16));
    if (u_out)
      ((uint2*)u_out)[wid * 16 + q] =
          make_uint2((unsigned)f2bf(dv * t0) | ((unsigned)f2bf(dv * t1) << 16),
                     (unsigned)f2bf(dv * t2) | ((unsigned)f2bf(dv * t3) << 16));
  }
}

// ====================== Fused MM building blocks (256 threads, 4 nodes x 4 feats) ======================
// NOTE (r12-r14): 512-thread variants produced ~2-4 GB phantom scratch traffic. Keep 256.
// NOTE (R1): named-register T14 queues + __launch_bounds__(256,3) — do not revert to arrays.
// NOTE (R6): R3's scalar mm_acc (broadcast A-reads) is the verified-best form.
// NOTE (R8): R7's agg64b->mm_e fusion REGRESSED (94us; gather TLP dropped 16x:
// 782 blocks vs 12500, 16 rows serial per wave, VALUBusy 15.7%). Reverted to the
// R6 split. Do not fuse row-gathers into MM-tile-sized grids.

__device__ __forceinline__ void mm_zero(float acc[4][4]) {
#pragma unroll
  for (int j = 0; j < 4; j++)
#pragma unroll
    for (int jj = 0; jj < 4; jj++) acc[j][jj] = 0.f;
}

__device__ __forceinline__ void mm_acc(const float* sA, const float* sW, int K,
                                       int nl0, int f0, float acc[4][4]) {
  for (int k = 0; k < K; k++) {
    float4 w = *(const float4*)(&sW[k * 64 + f0]);
#pragma unroll
    for (int j = 0; j < 4; j++) {
      float a = sA[(nl0 + j) * 68 + k];
      acc[j][0] += a * w.x; acc[j][1] += a * w.y; acc[j][2] += a * w.z; acc[j][3] += a * w.w;
    }
  }
}

// ---- named-register staging queue (single set live at a time) ----
#define WQ_ISSUE(W) do { const float4* _w = (const float4*)(W); \
  sw0 = _w[tid]; sw1 = _w[tid + 256]; sw2 = _w[tid + 512]; sw3 = _w[tid + 768]; } while (0)

#define WQ_COMMIT() do { float4* _s = (float4*)Ws; \
  _s[tid] = sw0; _s[tid + 256] = sw1; _s[tid + 512] = sw2; _s[tid + 768] = sw3; } while (0)

#define AQ_ISSUE1_F32(A, CNT, aa, cc, I) do { int _idx = tid + (I) * 256; \
  int _nl = _idx >> 4, _k4 = _idx & 15; int _g = gb + _nl; bool _ok = _g < n; \
  (aa) = _ok ? ((const float4*)(A))[_g * 16 + _k4] : make_float4(0.f, 0.f, 0.f, 0.f); \
  (cc) = ((CNT) != nullptr && _ok) ? (float)(CNT)[_g] : 1.f; } while (0)

#define AQ_ISSUE_F32(A, CNT) do { \
  AQ_ISSUE1_F32(A, CNT, sa0, sc0, 0); AQ_ISSUE1_F32(A, CNT, sa1, sc1, 1); \
  AQ_ISSUE1_F32(A, CNT, sa2, sc2, 2); AQ_ISSUE1_F32(A, CNT, sa3, sc3, 3); } while (0)

#define AQ_COMMIT1_F32(DST, SC, aa, cc, I) do { int _idx = tid + (I) * 256; \
  int _nl = _idx >> 4, _k4 = _idx & 15; float4 _v = (aa); \
  if (SC) { float _m = 1.f / fmaxf((cc), 1.f); _v.x *= _m; _v.y *= _m; _v.z *= _m; _v.w *= _m; } \
  *(float4*)(&(DST)[_nl * 68 + _k4 * 4]) = _v; } while (0)

#define AQ_COMMIT_F32(DST, SC) do { \
  AQ_COMMIT1_F32(DST, SC, sa0, sc0, 0); AQ_COMMIT1_F32(DST, SC, sa1, sc1, 1); \
  AQ_COMMIT1_F32(DST, SC, sa2, sc2, 2); AQ_COMMIT1_F32(DST, SC, sa3, sc3, 3); } while (0)

#define AQ_ISSUE1_BF16(A, bb, I) do { int _idx = tid + (I) * 256; \
  int _nl = _idx >> 4, _k4 = _idx & 15; int _g = gb + _nl; \
  (bb) = (_g < n) ? ((const uint2*)((A) + (size_t)_g * 64))[_k4] : make_uint2(0u, 0u); } while (0)

#define AQ_ISSUE_BF16(A) do { \
  AQ_ISSUE1_BF16(A, sb0, 0); AQ_ISSUE1_BF16(A, sb1, 1); \
  AQ_ISSUE1_BF16(A, sb2, 2); AQ_ISSUE1_BF16(A, sb3, 3); } while (0)

#define AQ_COMMIT1_BF16(bb, I) do { int _idx = tid + (I) * 256; \
  int _nl = _idx >> 4, _k4 = _idx & 15; float4 _v; \
  _v.x = bf2f((unsigned short)((bb).x & 0xFFFF)); \
  _v.y = bf2f((unsigned short)((bb).x >> 16)); \
  _v.z = bf2f((unsigned short)((bb).y & 0xFFFF)); \
  _v.w = bf2f((unsigned short)((bb).y >> 16)); \
  *(float4*)(&as[_nl * 68 + _k4 * 4]) = _v; } while (0)

#define AQ_COMMIT_BF16() do { \
  AQ_COMMIT1_BF16(sb0, 0); AQ_COMMIT1_BF16(sb1, 1); \
  AQ_COMMIT1_BF16(sb2, 2); AQ_COMMIT1_BF16(sb3, 3); } while (0)

// ---- phase-C chain: S2 = relu(aggIN'@W42_l + relu(aggIN'@W4_l + relu(aggHu'@W32_l +
//      relu(aggHw@W3_rel + sx@W3_root + b3)@W32_r + b32)@W4_r + b4)@W42_r + b42) ----
__global__ __launch_bounds__(256, 3)
void k_mm_chainC(const float* __restrict__ aggHw, const float* __restrict__ state_x,
                 const float* __restrict__ aggHu, const int* __restrict__ cnt_h,
                 const float* __restrict__ aggIN, const int* __restrict__ cnt_in,
                 const float* __restrict__ W3_rel, const float* __restrict__ W3_root,
                 const float* __restrict__ b3,
                 const float* __restrict__ W32_l, const float* __restrict__ W32_r,
                 const float* __restrict__ b32,
                 const float* __restrict__ W4_l, const float* __restrict__ W4_r,
                 const float* __restrict__ b4,
                 const float* __restrict__ W42_l, const float* __restrict__ W42_r,
                 const float* __restrict__ b42,
                 float* __restrict__ S2out, unsigned short* __restrict__ S2b,
                 const float* __restrict__ dinvS, int n) {
  __shared__ float Ws[4096];
  __shared__ float as[64 * 68];
  __shared__ float cs[64 * 68];
  const int tid = threadIdx.x;
  const int gb = blockIdx.x * 64;
  const int lane = tid & 63;
  const int fq = lane & 15, nq = lane >> 4;
  const int f0 = fq * 4;
  const int nl0 = (tid >> 6) * 16 + nq * 4;
  float acc[4][4];
  float4 sw0, sw1, sw2, sw3, sa0, sa1, sa2, sa3;
  float sc0, sc1, sc2, sc3;

  // ---- prologue: stage1 + all small scalars ----
  WQ_ISSUE(W3_rel);
  AQ_ISSUE_F32(aggHw, (const int*)nullptr);
  float rt0 = W3_root[tid];
  float rt1 = (tid < 64) ? W3_root[256 + tid] : 0.f;
  const int nlA = tid / 5, kA = tid - nlA * 5;
  float sxA = (gb + nlA < n) ? state_x[(size_t)(gb + nlA) * 5 + kA] : 0.f;
  const int iB = tid + 256;
  const int nlB = iB / 5, kB = iB - nlB * 5;
  float sxB = (tid < 64 && gb + nlB < n) ? state_x[(size_t)(gb + nlB) * 5 + kB] : 0.f;
  float4 rb3  = ((const float4*)b3)[fq];
  float4 rb32 = ((const float4*)b32)[fq];
  float4 rb4  = ((const float4*)b4)[fq];
  float4 rb42 = ((const float4*)b42)[fq];
  float rdv[4];
#pragma unroll
  for (int j = 0; j < 4; j++) {
    int g = gb + nl0 + j;
    rdv[j] = (g < n) ? dinvS[g] : 0.f;
  }
  WQ_COMMIT();                       // Ws <- W3_rel
  AQ_COMMIT_F32(as, false);          // as <- aggHw
  __syncthreads();

  // ---- phase 1: C1a + C1b ----
  WQ_ISSUE(W32_l);
  AQ_ISSUE_F32(aggHu, cnt_h);        // in flight under C1a+C1b
  mm_zero(acc);
  mm_acc(as, Ws, 64, nl0, f0, acc);  // C1a: aggHw @ W3_rel
  __syncthreads();
  Ws[tid] = rt0;                     // small commit: W3_root, state_x
  if (tid < 64) Ws[256 + tid] = rt1;
  as[nlA * 68 + kA] = sxA;
  if (tid < 64) as[nlB * 68 + kB] = sxB;
  __syncthreads();
  mm_acc(as, Ws, 5, nl0, f0, acc);   // C1b: + state_x @ W3_root
  {
    float bb[4] = {rb3.x, rb3.y, rb3.z, rb3.w};
#pragma unroll
    for (int j = 0; j < 4; j++)
#pragma unroll
      for (int jj = 0; jj < 4; jj++)
        cs[(nl0 + j) * 68 + f0 + jj] = fmaxf(acc[j][jj] + bb[jj], 0.f);
  }
  __syncthreads();
  WQ_COMMIT();                       // Ws <- W32_l
  AQ_COMMIT_F32(as, true);           // as <- aggHu'
  __syncthreads();

  // ---- phase 2: C2a ----
  WQ_ISSUE(W32_r);                   // in flight under C2a
  mm_zero(acc);
  mm_acc(as, Ws, 64, nl0, f0, acc);  // aggHu' @ W32_l
  __syncthreads();
  WQ_COMMIT();                       // Ws <- W32_r
  __syncthreads();

  // ---- phase 3: C2b ----
  WQ_ISSUE(W4_l);
  AQ_ISSUE_F32(aggIN, cnt_in);       // in flight under C2b
  mm_acc(cs, Ws, 64, nl0, f0, acc);  // + h3 @ W32_r
  __syncthreads();
  {
    float bb[4] = {rb32.x, rb32.y, rb32.z, rb32.w};
#pragma unroll
    for (int j = 0; j < 4; j++)
#pragma unroll
      for (int jj = 0; jj < 4; jj++)
        cs[(nl0 + j) * 68 + f0 + jj] = fmaxf(acc[j][jj] + bb[jj], 0.f);
  }
  WQ_COMMIT();                       // Ws <- W4_l
  AQ_COMMIT_F32(as, true);           // as <- aggIN' (lives through C4a)
  __syncthreads();

  // ---- phase 4: C3a ----
  WQ_ISSUE(W4_r);
  mm_zero(acc);
  mm_acc(as, Ws, 64, nl0, f0, acc);  // aggIN' @ W4_l
  __syncthreads();
  WQ_COMMIT();                       // Ws <- W4_r
  __syncthreads();

  // ---- phase 5: C3b ----
  WQ_ISSUE(W42_l);
  mm_acc(cs, Ws, 64, nl0, f0, acc);  // + h32 @ W4_r
  __syncthreads();
  {
    float bb[4] = {rb4.x, rb4.y, rb4.z, rb4.w};
#pragma unroll
    for (int j = 0; j < 4; j++)
#pragma unroll
      for (int jj = 0; jj < 4; jj++)
        cs[(nl0 + j) * 68 + f0 + jj] = fmaxf(acc[j][jj] + bb[jj], 0.f);
  }
  WQ_COMMIT();                       // Ws <- W42_l
  __syncthreads();

  // ---- phase 6: C4a ----
  WQ_ISSUE(W42_r);
  mm_zero(acc);
  mm_acc(as, Ws, 64, nl0, f0, acc);  // aggIN' @ W42_l (as untouched since phase 3)
  __syncthreads();
  WQ_COMMIT();                       // Ws <- W42_r
  __syncthreads();

  // ---- phase 7: C4b + epilogue ----
  mm_acc(cs, Ws, 64, nl0, f0, acc);  // + h4 @ W42_r
  {
    float bb[4] = {rb42.x, rb42.y, rb42.z, rb42.w};
#pragma unroll
    for (int j = 0; j < 4; j++) {
      int g = gb + nl0 + j;
      if (g < n) {
        float osc = rdv[j];
#pragma unroll
        for (int jj = 0; jj < 4; jj++) {
          int f = f0 + jj;
          float v = fmaxf(acc[j][jj] + bb[jj], 0.f);
          S2out[(size_t)g * 64 + f] = v;
          S2b[(size_t)g * 64 + f] = f2bf(v * osc);
        }
      }
    }
  }
}

// ---- phase-D quad MM: S1 = relu(S2@W2_0 + t1@W2_1 + t2@W2_2 + t3@W2_3 + b2); S1b = bf16 ----
__global__ __launch_bounds__(256, 4)
void k_mm_d(const float* __restrict__ S2, const unsigned short* __restrict__ t1b,
            const unsigned short* __restrict__ t2b, const unsigned short* __restrict__ t3b,
            const float* __restrict__ W2, const float* __restrict__ b2,
            float* __restrict__ S1, unsigned short* __restrict__ S1b, int n) {
  __shared__ float Ws[4096];
  __shared__ float as[64 * 68];
  const int tid = threadIdx.x;
  const int gb = blockIdx.x * 64;
  const int lane = tid & 63;
  const int fq = lane & 15, nq = lane >> 4;
  const int f0 = fq * 4;
  const int nl0 = (tid >> 6) * 16 + nq * 4;
  float acc[4][4];
  float4 sw0, sw1, sw2, sw3, sa0, sa1, sa2, sa3;
  float sc0, sc1, sc2, sc3;
  uint2 sb0, sb1, sb2, sb3;

  // prologue: stage0 (W2_0, S2 f32)
  WQ_ISSUE(W2);
  AQ_ISSUE_F32(S2, (const int*)nullptr);
  float4 rb2 = ((const float4*)b2)[fq];
  WQ_COMMIT();
  AQ_COMMIT_F32(as, false);
  __syncthreads();

  // phase 1: op0 (S2 f32)
  WQ_ISSUE(W2 + 4096);
  AQ_ISSUE_BF16(t1b);
  mm_zero(acc);
  mm_acc(as, Ws, 64, nl0, f0, acc);
  __syncthreads();
  WQ_COMMIT();
  AQ_COMMIT_BF16();
  __syncthreads();

  // phase 2: op1 (t1)
  WQ_ISSUE(W2 + 8192);
  AQ_ISSUE_BF16(t2b);
  mm_acc(as, Ws, 64, nl0, f0, acc);
  __syncthreads();
  WQ_COMMIT();
  AQ_COMMIT_BF16();
  __syncthreads();

  // phase 3: op2 (t2)
  WQ_ISSUE(W2 + 12288);
  AQ_ISSUE_BF16(t3b);
  mm_acc(as, Ws, 64, nl0, f0, acc);
  __syncthreads();
  WQ_COMMIT();
  AQ_COMMIT_BF16();
  __syncthreads();

  // phase 4: op3 (t3) + epilogue
  mm_acc(as, Ws, 64, nl0, f0, acc);
  {
    float bb[4] = {rb2.x, rb2.y, rb2.z, rb2.w};
#pragma unroll
    for (int j = 0; j < 4; j++) {
      int g = gb + nl0 + j;
      if (g < n) {
#pragma unroll
        for (int jj = 0; jj < 4; jj++) {
          int f = f0 + jj;
          float v = fmaxf(acc[j][jj] + bb[jj], 0.f);
          S1[(size_t)g * 64 + f] = v;
          S1b[(size_t)g * 64 + f] = f2bf(v);
        }
      }
    }
  }
}

// ---- phase-E MM + final projection: out = relu(aggSS'@W5_l + S1@W5_r + b5) @ Wl + bl ----
__global__ __launch_bounds__(256, 3)
void k_mm_e(const float* __restrict__ aggSS, const int* __restrict__ cnt_ss,
            const float* __restrict__ W5_l, const float* __restrict__ S1,
            const float* __restrict__ W5_r, const float* __restrict__ b5,
            const float* __restrict__ Wl, const float* __restrict__ bl,
            float* __restrict__ out, int n) {
  __shared__ float Ws[4096];
  __shared__ float as[64 * 68];
  __shared__ float cs[64 * 68];
  const int tid = threadIdx.x;
  const int gb = blockIdx.x * 64;
  const int lane = tid & 63;
  const int fq = lane & 15, nq = lane >> 4;
  const int f0 = fq * 4;
  const int nl0 = (tid >> 6) * 16 + nq * 4;
  float acc[4][4];
  float4 sw0, sw1, sw2, sw3, sa0, sa1, sa2, sa3;
  float sc0, sc1, sc2, sc3;

  // prologue: stage0 (W5_l, aggSS') + projection scalars
  WQ_ISSUE(W5_l);
  AQ_ISSUE_F32(aggSS, cnt_ss);
  float rwl0 = Wl[tid];
  float rwl1 = Wl[256 + tid];
  float4 rb5 = ((const float4*)b5)[fq];
  float rbl0 = bl[(2 * tid) & 7];
  float rbl1 = bl[(2 * tid + 1) & 7];
  WQ_COMMIT();
  AQ_COMMIT_F32(as, true);
  __syncthreads();

  // phase 1: aggSS' @ W5_l
  WQ_ISSUE(W5_r);
  AQ_ISSUE_F32(S1, (const int*)nullptr);
  mm_zero(acc);
  mm_acc(as, Ws, 64, nl0, f0, acc);
  __syncthreads();
  WQ_COMMIT();                       // Ws <- W5_r
  AQ_COMMIT_F32(cs, false);          // cs <- S1
  __syncthreads();

  // phase 2: + S1 @ W5_r, then project
  mm_acc(cs, Ws, 64, nl0, f0, acc);
  __syncthreads();
  {
    float bb[4] = {rb5.x, rb5.y, rb5.z, rb5.w};
#pragma unroll
    for (int j = 0; j < 4; j++)
#pragma unroll
      for (int jj = 0; jj < 4; jj++)
        as[(nl0 + j) * 68 + f0 + jj] = fmaxf(acc[j][jj] + bb[jj], 0.f);
  }
  Ws[tid] = rwl0;
  Ws[256 + tid] = rwl1;
  __syncthreads();
#pragma unroll
  for (int p = 0; p < 2; p++) {
    int idx = tid * 2 + p;
    int nl = idx >> 3, o = idx & 7;
    int g = gb + nl;
    if (g < n) {
      float a2 = (p == 0) ? rbl0 : rbl1;
#pragma unroll 8
      for (int k = 0; k < 64; k++) a2 += as[nl * 68 + k] * Ws[k * 8 + o];
      out[(size_t)g * 8 + o] = a2;
    }
  }
}

// ---------------- Host ----------------

extern "C" void kernel_launch(void* const* d_in, const int* in_sizes, int n_in,
                              void* d_out, int out_size, void* d_ws, size_t ws_size,
                              hipStream_t stream) {
  const float* game_x  = (const float*)d_in[0];
  const float* state_x = (const float*)d_in[1];
  const int*   ei_vv   = (const int*)d_in[2];
  const int*   et_vv   = (const int*)d_in[3];
  const int*   ei_h    = (const int*)d_in[4];
  const float* ew_h    = (const float*)d_in[5];
  const int*   ei_in   = (const int*)d_in[6];
  const int*   ei_ss   = (const int*)d_in[7];
  const float* W1_rel  = (const float*)d_in[8];
  const float* W1_root = (const float*)d_in[9];
  const float* b1      = (const float*)d_in[10];
  const float* W12     = (const float*)d_in[11];
  const float* b12     = (const float*)d_in[12];
  const float* W2      = (const float*)d_in[13];
  const float* b2      = (const float*)d_in[14];
  const float* W3_rel  = (const float*)d_in[15];
  const float* W3_root = (const float*)d_in[16];
  const float* b3      = (const float*)d_in[17];
  const float* W32_l   = (const float*)d_in[18];
  const float* W32_r   = (const float*)d_in[19];
  const float* b32     = (const float*)d_in[20];
  const float* W4_l    = (const float*)d_in[21];
  const float* W4_r    = (const float*)d_in[22];
  const float* b4      = (const float*)d_in[23];
  const float* W42_l   = (const float*)d_in[24];
  const float* W42_r   = (const float*)d_in[25];
  const float* b42     = (const float*)d_in[26];
  const float* W5_l    = (const float*)d_in[27];
  const float* W5_r    = (const float*)d_in[28];
  const float* b5      = (const float*)d_in[29];
  const float* Wl      = (const float*)d_in[30];
  const float* bl      = (const float*)d_in[31];

  // Workspace (4B slots), peak 26.05M slots = 104.2 MiB.
  float* ws = (float*)d_ws;
  int*   cnt_all = (int*)(ws + 0);              // 250K (vv|h|in|ss)
  int*   rs_all  = (int*)(ws + 250000);         // 250K (graph-local values)
  int*   bcnt    = (int*)(ws + 500000);         // 512
  int*   bbase   = (int*)(ws + 500512);         // 512
  int*   cb      = (int*)(ws + 501024);         // 512
  int*   srcs_ss = (int*)(ws + 760000);         // 0.8M  (lives through phase E)
  float4* x_pad  = (float4*)(ws + 1600000);     // 800K
  float4* h1p    = (float4*)(ws + 2400000);
  float4* h2p    = (float4*)(ws + 3200000);
  float4* h3p    = (float4*)(ws + 4000000);
  float4* ra4all = (float4*)(ws + 4800000);     // [NVV][5] float4 = 2.0M slots -> 6.8M
  float* dinvS   = ws + 6800000;                // 50K
  unsigned short* gx16 = (unsigned short*)(ws + 6850000);  // 3.2M slots -> 10.05M
  unsigned* temp_vv    = (unsigned*)(ws + 6850000);        // 1.6M, overlays gx16 front (dead before combine)
  float* aggHw = ws + 10050000;                 // 3.2M
  float* aggHu = ws + 13250000;                 // 3.2M
  float* aggIN = ws + 16450000;                 // 3.2M
  float* S1    = ws + 19650000;                 // 3.2M
  float* S2    = ws + 22850000;                 // 3.2M -> ends 26.05M
  // fill temps overlay agg regions (dead until phase B):
  uint2*    temp_h  = (uint2*)aggHw;
  unsigned* temp_in = (unsigned*)(aggHw + 1600000);
  unsigned* temp_ss = (unsigned*)(aggHw + 2400000);
  // overlays (dead-before-write verified in stream order):
  unsigned short* S2b = (unsigned short*)(ws + 4800000);     // in ra4all region (dead after combine_gx)
  unsigned short* u1b = (unsigned short*)(aggHw + 1600000);  // hop1 aux; aggHw dead after chainC
  float*          aggSS = aggHw + 1600000;                   // phase E (after u1b dead)
  unsigned short* t1b = (unsigned short*)aggHu;              // aggHu dead after chainC
  unsigned short* t2b = (unsigned short*)(aggHu + 1600000);
  unsigned short* t3b = (unsigned short*)aggIN;              // aggIN dead after chainC
  unsigned short* S1b = (unsigned short*)(aggIN + 1600000);  // k_mm_d shadow
  unsigned* payload_vv = (unsigned*)S1;                      // dead after phase A
  unsigned short* u2b  = (unsigned short*)S1;                // hop2 aux; S1 written later by k_mm_d
  int2*     eh         = (int2*)S2;                          // dead after aggB; S2 written by chainC
  int*      srcs_in    = (int*)(S2 + 1600000);

  const int* src_vv = ei_vv;  const int* dst_vv = ei_vv + E_VV;
  const int* src_h  = ei_h;   const int* dst_h  = ei_h + E_H;
  const int* src_in = ei_in;  const int* dst_in = ei_in + E_IN;
  const int* src_ss = ei_ss;  const int* dst_ss = ei_ss + E_SS;

  auto nblk = [](long long n) { return dim3((unsigned)((n + 255) / 256)); };
  const int NB64 = (NSV + 3) / 4;
  const int NB   = (NSV + 63) / 64;
  const int GC   = (ETOT + TC - 1) / TC;
  const int NBVV4 = (NVV + 63) / 64;   // 4 lanes/node vv kernels

  int* cnt_h  = cnt_all + H_ROW;
  int* cnt_in = cnt_all + IN_ROW;
  int* cnt_ss = cnt_all + SS_ROW;
  int* rs_vv  = rs_all;
  int* rs_h   = rs_all + H_ROW;
  int* rs_in  = rs_all + IN_ROW;
  int* rs_ss  = rs_all + SS_ROW;

  // ---- CSR build (fused) ----
  hipMemsetAsync(bcnt, 0, NBTOT * sizeof(int), stream);
  k_bucket_count<<<GC, 256, 0, stream>>>(dst_vv, dst_h, dst_in, dst_ss, bcnt);
  k_bucket_scan<<<1, 512, 0, stream>>>(bcnt, bbase, cb);
  k_fill_s1_all<<<SB1, 256, 0, stream>>>(src_vv, dst_vv, et_vv, src_h, dst_h, ew_h,
                                         src_in, dst_in, src_ss, dst_ss, cb,
                                         temp_vv, temp_h, temp_in, temp_ss);
  k_fill_s2_all<<<NBTOT, 256, 0, stream>>>(temp_vv, temp_h, temp_in, temp_ss, bbase,
                                           payload_vv, eh, srcs_in, srcs_ss,
                                           rs_all, cnt_all, game_x, x_pad, dinvS);

  // ---- Phase A: v-graph 5-dim (4 lanes/node) ----
  k_vv_pass1<<<NBVV4, 256, 0, stream>>>(x_pad, rs_vv, cnt_all, payload_vv, ra4all, h1p);
  k_vv_hop<<<NBVV4, 256, 0, stream>>>(h1p, rs_vv, cnt_all, payload_vv, h2p);
  k_vv_hop<<<NBVV4, 256, 0, stream>>>(h2p, rs_vv, cnt_all, payload_vv, h3p);
  k_combine_gx<<<dim3((NVV + 31) / 32), 256, 0, stream>>>(x_pad, ra4all, h1p, h2p, h3p,
                                                          W1_rel, W1_root, b1, W12, b12, gx16);

  // ---- Phase B: fused 64-dim bf16 gathers ----
  k_aggB<<<2 * NB64, 256, 0, stream>>>(gx16, rs_h, cnt_h, eh, rs_in, cnt_in, srcs_in,
                                       aggHw, aggHu, aggIN, NB64);

  // ---- Phase C: fused 4-MM chain -> S2 (+ dinv-prescaled bf16 shadow) ----
  k_mm_chainC<<<NB, 256, 0, stream>>>(aggHw, state_x, aggHu, cnt_h, aggIN, cnt_in,
                                      W3_rel, W3_root, b3, W32_l, W32_r, b32,
                                      W4_l, W4_r, b4, W42_l, W42_r, b42,
                                      S2, S2b, dinvS, NSV);

  // ---- Phase D: TAG on s-s (prescaled bf16 hops) + fused quad MM ----
  k_tag64b<<<NB64, 256, 0, stream>>>(S2b, rs_ss, cnt_ss, srcs_ss, dinvS, t1b, u1b, NSV);
  k_tag64b<<<NB64, 256, 0, stream>>>(u1b, rs_ss, cnt_ss, srcs_ss, dinvS, t2b, u2b, NSV);
  k_tag64b<<<NB64, 256, 0, stream>>>(u2b, rs_ss, cnt_ss, srcs_ss, dinvS, t3b, nullptr, NSV);
  k_mm_d<<<NB, 256, 0, stream>>>(S2, t1b, t2b, t3b, W2, b2, S1, S1b, NSV);

  // ---- Phase E: SAGE on s-s + final projection ----
  k_agg64b<<<NB64, 256, 0, stream>>>(S1b, rs_ss, cnt_ss, srcs_ss, aggSS, NSV);
  k_mm_e<<<NB, 256, 0, stream>>>(aggSS, cnt_ss, W5_l, S1, W5_r, b5, Wl, bl, (float*)d_out, NSV);
}

// Round 9
// 575.613 us; speedup vs baseline: 1.1276x; 1.0374x over previous
//
#include <hip/hip_runtime.h>

#define NVV 100000
#define NSV 50000
#define E_VV 1600000
#define E_H  800000
#define E_IN 800000
#define E_SS 800000
#define ETOT 4000000
#define DIN 5
#define H_ROW 100000          // concatenated cnt/rs space: vv|h|in|ss
#define IN_ROW 150000
#define SS_ROW 200000
#define NROWS 250000
#define POS_H  E_VV
#define POS_IN (E_VV + E_H)
#define POS_SS (E_VV + E_H + E_IN)
#define NBUK 196              // vv buckets (dst >> 9)
#define NBUKS 98              // NSV-graph buckets
#define NBTOT 490             // vv|h|in|ss bucket space
#define BUK_H  196
#define BUK_IN 294
#define BUK_SS 392
#define BSHIFT 9
#define T1 4096               // edges per fill-stage-1 block
#define TC 16384              // edges per bucket-count block
#define G1VV 391              // ceil(E_VV/T1)
#define G1S  196              // ceil(E_H/T1)
#define SB1  (G1VV + 3 * G1S) // 979 fused stage-1 blocks

__device__ __forceinline__ unsigned short f2bf(float x) {
  unsigned b = __float_as_uint(x);
  return (unsigned short)((b + 0x7FFFu + ((b >> 16) & 1u)) >> 16);
}
__device__ __forceinline__ float bf2f(unsigned short u) {
  return __uint_as_float(((unsigned)u) << 16);
}
#define BFLO(u) __uint_as_float((u) << 16)
#define BFHI(u) __uint_as_float((u) & 0xFFFF0000u)
#define PK2(a, b) ((unsigned)f2bf(a) | ((unsigned)f2bf(b) << 16))

// ====================== CSR build: bucket counts -> bases -> fused binned fills ======================

__global__ __launch_bounds__(256)
void k_bucket_count(const int* __restrict__ d_vv, const int* __restrict__ d_h,
                    const int* __restrict__ d_in, const int* __restrict__ d_ss,
                    int* __restrict__ bcnt) {
  __shared__ int h[NBTOT];
  const int tid = threadIdx.x;
  for (int i = tid; i < NBTOT; i += 256) h[i] = 0;
  __syncthreads();
  const int base = blockIdx.x * TC;
#pragma unroll 4
  for (int k = 0; k < TC / 256; k++) {
    int e = base + k * 256 + tid;
    int bi = -1;
    if (e < E_VV) bi = d_vv[e] >> BSHIFT;
    else if (e < POS_IN) bi = BUK_H + (d_h[e - POS_H] >> BSHIFT);
    else if (e < POS_SS) bi = BUK_IN + (d_in[e - POS_IN] >> BSHIFT);
    else if (e < ETOT) bi = BUK_SS + (d_ss[e - POS_SS] >> BSHIFT);
    if (bi >= 0) atomicAdd(&h[bi], 1);
  }
  __syncthreads();
  for (int i = tid; i < NBTOT; i += 256) if (h[i]) atomicAdd(&bcnt[i], h[i]);
}

__global__ __launch_bounds__(512)
void k_bucket_scan(const int* __restrict__ bcnt, int* __restrict__ bbase, int* __restrict__ cb) {
  __shared__ int sd[512];
  int t = threadIdx.x;
  int v = (t < NBTOT) ? bcnt[t] : 0;
  sd[t] = v; __syncthreads();
  for (int off = 1; off < 512; off <<= 1) {
    int x = (t >= off) ? sd[t - off] : 0;
    __syncthreads();
    sd[t] += x;
    __syncthreads();
  }
  int segstart = (t < BUK_H) ? 0 : (t < BUK_IN) ? BUK_H : (t < BUK_SS) ? BUK_IN : BUK_SS;
  int excl = ((t > 0) ? sd[t - 1] : 0) - ((segstart > 0) ? sd[segstart - 1] : 0);
  if (t < NBTOT) { bbase[t] = excl; cb[t] = excl; }
}

// ---- fused stage 1: all 4 graphs, bucket-grouped binning, coalesced run writes ----
__global__ __launch_bounds__(256)
void k_fill_s1_all(const int* __restrict__ s_vv, const int* __restrict__ d_vv,
                   const int* __restrict__ et,
                   const int* __restrict__ s_h, const int* __restrict__ d_h,
                   const float* __restrict__ ew,
                   const int* __restrict__ s_in, const int* __restrict__ d_in,
                   const int* __restrict__ s_ss, const int* __restrict__ d_ss,
                   int* __restrict__ cb,
                   unsigned* __restrict__ temp_vv, uint2* __restrict__ temp_h,
                   unsigned* __restrict__ temp_in, unsigned* __restrict__ temp_ss) {
  __shared__ int hist[NBUK], lbase[NBUK], run[NBUK], gb[NBUK];
  __shared__ int sc[256];
  __shared__ unsigned stage[T1];
  __shared__ unsigned stageW[T1];
  __shared__ int gpos[T1];
  const int tid = threadIdx.x;
  const int b = blockIdx.x;
  int g, tile;
  if (b < G1VV) { g = 0; tile = b; }
  else if (b < G1VV + G1S) { g = 1; tile = b - G1VV; }
  else if (b < G1VV + 2 * G1S) { g = 2; tile = b - G1VV - G1S; }
  else { g = 3; tile = b - G1VV - 2 * G1S; }
  const int ne = (g == 0) ? E_VV : E_H;
  const int nbuk = (g == 0) ? NBUK : NBUKS;
  const int cboff = (g == 0) ? 0 : (g == 1) ? BUK_H : (g == 2) ? BUK_IN : BUK_SS;
  const int* S = (g == 0) ? s_vv : (g == 1) ? s_h : (g == 2) ? s_in : s_ss;
  const int* D = (g == 0) ? d_vv : (g == 1) ? d_h : (g == 2) ? d_in : d_ss;
  const int base = tile * T1;
  const int nvalid = min(T1, ne - base);
  for (int i = tid; i < nbuk; i += 256) { hist[i] = 0; run[i] = 0; }
  __syncthreads();
  int dv[16]; unsigned pk[16], pkw[16];
#pragma unroll
  for (int k = 0; k < 16; k++) {
    int e = base + k * 256 + tid;
    if (e - base < nvalid) {
      int d = D[e];
      dv[k] = d;
      if (g == 0) pk[k] = (unsigned)(((d & 511) << 19) | (et[e] << 17) | S[e]);
      else pk[k] = (unsigned)(((d & 511) << 17) | S[e]);
      if (g == 1) pkw[k] = (unsigned)__float_as_int(ew[e]);
      atomicAdd(&hist[d >> BSHIFT], 1);
    } else dv[k] = -1;
  }
  __syncthreads();
  int my = (tid < nbuk) ? hist[tid] : 0;
  sc[tid] = my; __syncthreads();
  for (int off = 1; off < 256; off <<= 1) {
    int t = (tid >= off) ? sc[tid - off] : 0;
    __syncthreads();
    sc[tid] += t;
    __syncthreads();
  }
  if (tid < nbuk) {
    lbase[tid] = sc[tid] - my;
    gb[tid] = my ? atomicAdd(&cb[cboff + tid], my) : 0;
  }
  __syncthreads();
#pragma unroll
  for (int k = 0; k < 16; k++) {
    if (dv[k] >= 0) {
      int bu = dv[k] >> BSHIFT;
      int loc = atomicAdd(&run[bu], 1);
      int li = lbase[bu] + loc;
      stage[li] = pk[k];
      if (g == 1) stageW[li] = pkw[k];
      gpos[li] = gb[bu] + loc;
    }
  }
  __syncthreads();
  if (g == 0)      for (int i = tid; i < nvalid; i += 256) temp_vv[gpos[i]] = stage[i];
  else if (g == 1) for (int i = tid; i < nvalid; i += 256) temp_h[gpos[i]] = make_uint2(stage[i], stageW[i]);
  else if (g == 2) for (int i = tid; i < nvalid; i += 256) temp_in[gpos[i]] = stage[i];
  else             for (int i = tid; i < nvalid; i += 256) temp_ss[gpos[i]] = stage[i];
}

// ---- fused stage 2 ----
__global__ __launch_bounds__(256)
void k_fill_s2_all(const unsigned* __restrict__ temp_vv, const uint2* __restrict__ temp_h,
                   const unsigned* __restrict__ temp_in, const unsigned* __restrict__ temp_ss,
                   const int* __restrict__ bbase,
                   unsigned* __restrict__ payload_vv, int2* __restrict__ eh,
                   int* __restrict__ srcs_in, int* __restrict__ srcs_ss,
                   int* __restrict__ rs_all, int* __restrict__ cnt_all,
                   const float* __restrict__ x, float4* __restrict__ xp,
                   float* __restrict__ dinvS) {
  __shared__ int lcnt[512], lpos[512];
  __shared__ int sc[256];
  const int b = blockIdx.x, tid = threadIdx.x;
  int g, lb;
  if (b < BUK_H) { g = 0; lb = b; }
  else if (b < BUK_IN) { g = 1; lb = b - BUK_H; }
  else if (b < BUK_SS) { g = 2; lb = b - BUK_IN; }
  else { g = 3; lb = b - BUK_SS; }
  const int d0 = lb << BSHIFT;
  const int nrows = (g == 0) ? NVV : NSV;
  const int rowbase = (g == 0) ? 0 : (g == 1) ? H_ROW : (g == 2) ? IN_ROW : SS_ROW;
  const int ne = (g == 0) ? E_VV : E_H;
  const int lastb = (g == 0) ? NBUK - 1 : NBUKS - 1;
  const int shift = (g == 0) ? 19 : 17;
  lcnt[tid] = 0; lcnt[tid + 256] = 0;
  __syncthreads();
  const int gstart = bbase[b];
  const int gend = (lb == lastb) ? ne : bbase[b + 1];
  if (g == 1) {
    for (int i = gstart + tid; i < gend; i += 256) atomicAdd(&lcnt[temp_h[i].x >> 17], 1);
  } else {
    const unsigned* tp = (g == 0) ? temp_vv : (g == 2) ? temp_in : temp_ss;
    for (int i = gstart + tid; i < gend; i += 256) atomicAdd(&lcnt[tp[i] >> shift], 1);
  }
  __syncthreads();
  int c0 = lcnt[2 * tid], c1 = lcnt[2 * tid + 1];
  int ps = c0 + c1;
  sc[tid] = ps; __syncthreads();
  for (int off = 1; off < 256; off <<= 1) {
    int x2 = (tid >= off) ? sc[tid - off] : 0;
    __syncthreads();
    sc[tid] += x2;
    __syncthreads();
  }
  int basep = gstart + sc[tid] - ps;
  lpos[2 * tid] = basep;
  lpos[2 * tid + 1] = basep + c0;
  __syncthreads();
  for (int d = tid; d < 512; d += 256) {
    int gd = d0 + d;
    if (gd < nrows) {
      rs_all[rowbase + gd] = lpos[d];
      cnt_all[rowbase + gd] = lcnt[d];
      if (g == 0) {
        float dc = (float)lcnt[d];
        float di = dc > 0.f ? rsqrtf(dc) : 0.f;
        const float* xr = x + (size_t)gd * 5;
        xp[gd * 2]     = make_float4(xr[0], xr[1], xr[2], xr[3]);
        xp[gd * 2 + 1] = make_float4(xr[4], di, 0.f, 0.f);
      } else if (g == 3) {
        float dc = (float)lcnt[d];
        dinvS[gd] = dc > 0.f ? rsqrtf(dc) : 0.f;
      }
    }
  }
  __syncthreads();
  if (g == 0) {
    for (int i = gstart + tid; i < gend; i += 256) {
      unsigned en = temp_vv[i];
      int pos = atomicAdd(&lpos[en >> 19], 1);
      payload_vv[pos] = en & 0x7FFFFu;
    }
  } else if (g == 1) {
    for (int i = gstart + tid; i < gend; i += 256) {
      uint2 en = temp_h[i];
      int pos = atomicAdd(&lpos[en.x >> 17], 1);
      eh[pos] = make_int2((int)(en.x & 0x1FFFFu), (int)en.y);
    }
  } else if (g == 2) {
    for (int i = gstart + tid; i < gend; i += 256) {
      unsigned en = temp_in[i];
      int pos = atomicAdd(&lpos[en >> 17], 1);
      srcs_in[pos] = (int)(en & 0x1FFFFu);
    }
  } else {
    for (int i = gstart + tid; i < gend; i += 256) {
      unsigned en = temp_ss[i];
      int pos = atomicAdd(&lpos[en >> 17], 1);
      srcs_ss[pos] = (int)(en & 0x1FFFFu);
    }
  }
}

// ====================== Phase A: v-graph (5-dim, padded rows, 4 lanes/node) ======================

__global__ __launch_bounds__(256)
void k_vv_pass1(const float4* __restrict__ xp,
                const int* __restrict__ rowstart, const int* __restrict__ cnt,
                const unsigned* __restrict__ payload,
                float4* __restrict__ ra4all, float4* __restrict__ h1p) {
  const int tid = threadIdx.x;
  const int d = blockIdx.x * 64 + (tid >> 2);
  if (d >= NVV) return;
  const int q = tid & 3;
  int rs = rowstart[d], c = cnt[d];
  float a0[5] = {0,0,0,0,0}, a1[5] = {0,0,0,0,0}, a2[5] = {0,0,0,0,0}, h[5] = {0,0,0,0,0};
  float c0 = 0.f, c1 = 0.f, c2 = 0.f;
  int j = q;
  for (; j + 4 < c; j += 8) {
    unsigned pA = payload[rs + j], pB = payload[rs + j + 4];
    int sA = pA & 0x1FFFF, rA = pA >> 17;
    int sB = pB & 0x1FFFF, rB = pB >> 17;
    float4 xA0 = xp[sA * 2], xA1 = xp[sA * 2 + 1];
    float4 xB0 = xp[sB * 2], xB1 = xp[sB * 2 + 1];
    float xsA[5] = {xA0.x, xA0.y, xA0.z, xA0.w, xA1.x};
    float xsB[5] = {xB0.x, xB0.y, xB0.z, xB0.w, xB1.x};
    float wA = xA1.y, wB = xB1.y;
    float mA0 = (rA == 0) ? 1.f : 0.f, mA1 = (rA == 1) ? 1.f : 0.f, mA2 = (rA == 2) ? 1.f : 0.f;
    float mB0 = (rB == 0) ? 1.f : 0.f, mB1 = (rB == 1) ? 1.f : 0.f, mB2 = (rB == 2) ? 1.f : 0.f;
    c0 += mA0 + mB0; c1 += mA1 + mB1; c2 += mA2 + mB2;
#pragma unroll
    for (int k = 0; k < 5; k++) {
      h[k] += wA * xsA[k] + wB * xsB[k];
      a0[k] += mA0 * xsA[k] + mB0 * xsB[k];
      a1[k] += mA1 * xsA[k] + mB1 * xsB[k];
      a2[k] += mA2 * xsA[k] + mB2 * xsB[k];
    }
  }
  for (; j < c; j += 4) {
    unsigned p = payload[rs + j];
    int s = p & 0x1FFFF, r = p >> 17;
    float4 x0 = xp[s * 2], x1 = xp[s * 2 + 1];
    float xs[5] = {x0.x, x0.y, x0.z, x0.w, x1.x};
    float wsc = x1.y;
    float m0 = (r == 0) ? 1.f : 0.f, m1 = (r == 1) ? 1.f : 0.f, m2 = (r == 2) ? 1.f : 0.f;
    c0 += m0; c1 += m1; c2 += m2;
#pragma unroll
    for (int k = 0; k < 5; k++) {
      h[k] += wsc * xs[k];
      a0[k] += m0 * xs[k]; a1[k] += m1 * xs[k]; a2[k] += m2 * xs[k];
    }
  }
  // quad butterfly reduce: every lane ends with the full sums
#pragma unroll
  for (int k = 0; k < 5; k++) {
    a0[k] += __shfl_xor(a0[k], 1); a0[k] += __shfl_xor(a0[k], 2);
    a1[k] += __shfl_xor(a1[k], 1); a1[k] += __shfl_xor(a1[k], 2);
    a2[k] += __shfl_xor(a2[k], 1); a2[k] += __shfl_xor(a2[k], 2);
    h[k]  += __shfl_xor(h[k], 1);  h[k]  += __shfl_xor(h[k], 2);
  }
  c0 += __shfl_xor(c0, 1); c0 += __shfl_xor(c0, 2);
  c1 += __shfl_xor(c1, 1); c1 += __shfl_xor(c1, 2);
  c2 += __shfl_xor(c2, 1); c2 += __shfl_xor(c2, 2);
  float dv = xp[d * 2 + 1].y;
  float4* ra4 = ra4all + d * 5;
  if (q == 0) {
    ra4[0] = make_float4(a0[0], a0[1], a0[2], a0[3]);
    ra4[1] = make_float4(a0[4], a1[0], a1[1], a1[2]);
  } else if (q == 1) {
    ra4[2] = make_float4(a1[3], a1[4], a2[0], a2[1]);
    ra4[3] = make_float4(a2[2], a2[3], a2[4], c0);
  } else if (q == 2) {
    ra4[4] = make_float4(c1, c2, 0.f, 0.f);
  } else {
    h1p[d * 2]     = make_float4(dv * h[0], dv * h[1], dv * h[2], dv * h[3]);
    h1p[d * 2 + 1] = make_float4(dv * h[4], dv, 0.f, 0.f);
  }
}

__global__ __launch_bounds__(256)
void k_vv_hop(const float4* __restrict__ hinp,
              const int* __restrict__ rowstart, const int* __restrict__ cnt,
              const unsigned* __restrict__ payload, float4* __restrict__ houtp) {
  const int tid = threadIdx.x;
  const int d = blockIdx.x * 64 + (tid >> 2);
  if (d >= NVV) return;
  const int q = tid & 3;
  int rs = rowstart[d], c = cnt[d];
  float h[5] = {0,0,0,0,0};
  int j = q;
  for (; j + 4 < c; j += 8) {
    unsigned p0 = payload[rs + j], p1 = payload[rs + j + 4];
    int s0 = p0 & 0x1FFFF, s1 = p1 & 0x1FFFF;
    float4 a0 = hinp[s0 * 2], b0 = hinp[s0 * 2 + 1];
    float4 a1 = hinp[s1 * 2], b1 = hinp[s1 * 2 + 1];
    float w0 = b0.y, w1 = b1.y;
    h[0] += w0 * a0.x + w1 * a1.x;
    h[1] += w0 * a0.y + w1 * a1.y;
    h[2] += w0 * a0.z + w1 * a1.z;
    h[3] += w0 * a0.w + w1 * a1.w;
    h[4] += w0 * b0.x + w1 * b1.x;
  }
  for (; j < c; j += 4) {
    int s = payload[rs + j] & 0x1FFFF;
    float4 x0 = hinp[s * 2], x1 = hinp[s * 2 + 1];
    float wsc = x1.y;
    h[0] += wsc * x0.x; h[1] += wsc * x0.y; h[2] += wsc * x0.z; h[3] += wsc * x0.w;
    h[4] += wsc * x1.x;
  }
#pragma unroll
  for (int k = 0; k < 5; k++) {
    h[k] += __shfl_xor(h[k], 1);
    h[k] += __shfl_xor(h[k], 2);
  }
  float dv = hinp[d * 2 + 1].y;
  if (q == 0)      houtp[d * 2]     = make_float4(dv * h[0], dv * h[1], dv * h[2], dv * h[3]);
  else if (q == 1) houtp[d * 2 + 1] = make_float4(dv * h[4], dv, 0.f, 0.f);
}

// 8 nodes/thread, Ws column in 35 VGPRs, float4 relall loads.
__global__ __launch_bounds__(256)
void k_combine_gx(const float4* __restrict__ xp,
                  const float4* __restrict__ ra4all,
                  const float4* __restrict__ h1p, const float4* __restrict__ h2p,
                  const float4* __restrict__ h3p,
                  const float* __restrict__ W1_rel, const float* __restrict__ W1_root,
                  const float* __restrict__ b1,
                  const float* __restrict__ W12, const float* __restrict__ b12,
                  unsigned short* __restrict__ gx16) {
  __shared__ float Ws[7 * 320];
  __shared__ float bs[64];
  int tid = threadIdx.x;
  for (int i = tid; i < 320; i += 256) {
    Ws[i]        = W1_root[i] + W12[i];
    Ws[320 + i]  = W1_rel[i];
    Ws[640 + i]  = W1_rel[320 + i];
    Ws[960 + i]  = W1_rel[640 + i];
    Ws[1280 + i] = W12[320 + i];
    Ws[1600 + i] = W12[640 + i];
    Ws[1920 + i] = W12[960 + i];
  }
  if (tid < 64) bs[tid] = b1[tid] + b12[tid];
  __syncthreads();
  const int f = tid & 63;
  const int grp = tid >> 6;
  float wcol[35];
#pragma unroll
  for (int t = 0; t < 35; t++) wcol[t] = Ws[t * 64 + f];
  const float bias = bs[f];
  const int v0 = blockIdx.x * 32 + grp * 8;
  for (int n = 0; n < 8; n++) {
    int v = v0 + n;
    if (v >= NVV) return;
    float in[35];
    {
      float4 x0 = xp[v * 2], x1 = xp[v * 2 + 1];
      in[0] = x0.x; in[1] = x0.y; in[2] = x0.z; in[3] = x0.w; in[4] = x1.x;
    }
    {
      const float4* ra = ra4all + v * 5;
      float4 r0 = ra[0], r1 = ra[1], r2 = ra[2], r3 = ra[3], r4 = ra[4];
      float i0 = 1.0f / fmaxf(r3.w, 1.0f);
      float i1 = 1.0f / fmaxf(r4.x, 1.0f);
      float i2 = 1.0f / fmaxf(r4.y, 1.0f);
      in[5]  = r0.x * i0; in[6]  = r0.y * i0; in[7]  = r0.z * i0; in[8]  = r0.w * i0; in[9]  = r1.x * i0;
      in[10] = r1.y * i1; in[11] = r1.z * i1; in[12] = r1.w * i1; in[13] = r2.x * i1; in[14] = r2.y * i1;
      in[15] = r2.z * i2; in[16] = r2.w * i2; in[17] = r3.x * i2; in[18] = r3.y * i2; in[19] = r3.z * i2;
    }
    {
      float4 a = h1p[v * 2], b = h1p[v * 2 + 1];
      in[20] = a.x; in[21] = a.y; in[22] = a.z; in[23] = a.w; in[24] = b.x;
      a = h2p[v * 2]; b = h2p[v * 2 + 1];
      in[25] = a.x; in[26] = a.y; in[27] = a.z; in[28] = a.w; in[29] = b.x;
      a = h3p[v * 2]; b = h3p[v * 2 + 1];
      in[30] = a.x; in[31] = a.y; in[32] = a.z; in[33] = a.w; in[34] = b.x;
    }
    float acc = bias;
#pragma unroll
    for (int t = 0; t < 35; t++) acc += in[t] * wcol[t];
    gx16[v * 64 + f] = f2bf(acc);
  }
}

// ================= 64-dim CSR gathers (R9 oct-slot: 8 edges / wave-load, 16 B/lane) =================
// lane = (h in 0..7 edge slot, q in 0..7 feature group); lane q holds features 8q..8q+7
// as uint4; slot h walks edges j ≡ h (mod 8). One wave load = 8 rows (1 KB).
// Reduce: shfl_xor 8+16+32; h==0 lanes (0..7) write 2x float4 / packed uint4.

__global__ __launch_bounds__(256)
void k_aggB(const unsigned short* __restrict__ X16,
            const int* __restrict__ rs_h, const int* __restrict__ cnt_h,
            const int2* __restrict__ eh,
            const int* __restrict__ rs_in, const int* __restrict__ cnt_in,
            const int* __restrict__ srcs_in,
            float* __restrict__ outw, float* __restrict__ outu, float* __restrict__ outIN,
            int nb64) {
  const uint4* X4 = (const uint4*)X16;
  int bb = blockIdx.x;
  int lane = threadIdx.x & 63;
  int q = lane & 7;
  int h = lane >> 3;
  if (bb < nb64) {
    int wid = bb * 4 + (threadIdx.x >> 6);
    if (wid >= NSV) return;
    int rs = rs_h[wid], c = cnt_h[wid];
    int nh = (c - h + 7) >> 3;
    const int2* ep = eh + rs + h;
    float au0 = 0.f, au1 = 0.f, au2 = 0.f, au3 = 0.f, au4 = 0.f, au5 = 0.f, au6 = 0.f, au7 = 0.f;
    float aw0 = 0.f, aw1 = 0.f, aw2 = 0.f, aw3 = 0.f, aw4 = 0.f, aw5 = 0.f, aw6 = 0.f, aw7 = 0.f;
    int k = 0;
    for (; k + 2 <= nh; k += 2) {
      int2 p0 = ep[8 * k], p1 = ep[8 * k + 8];
      uint4 r0 = X4[(unsigned)p0.x * 8 + q];
      uint4 r1 = X4[(unsigned)p1.x * 8 + q];
      float w0 = __int_as_float(p0.y), w1 = __int_as_float(p1.y);
      float v00 = BFLO(r0.x), v01 = BFHI(r0.x), v02 = BFLO(r0.y), v03 = BFHI(r0.y);
      float v04 = BFLO(r0.z), v05 = BFHI(r0.z), v06 = BFLO(r0.w), v07 = BFHI(r0.w);
      float v10 = BFLO(r1.x), v11 = BFHI(r1.x), v12 = BFLO(r1.y), v13 = BFHI(r1.y);
      float v14 = BFLO(r1.z), v15 = BFHI(r1.z), v16 = BFLO(r1.w), v17 = BFHI(r1.w);
      au0 += v00 + v10; au1 += v01 + v11; au2 += v02 + v12; au3 += v03 + v13;
      au4 += v04 + v14; au5 += v05 + v15; au6 += v06 + v16; au7 += v07 + v17;
      aw0 += w0 * v00 + w1 * v10; aw1 += w0 * v01 + w1 * v11;
      aw2 += w0 * v02 + w1 * v12; aw3 += w0 * v03 + w1 * v13;
      aw4 += w0 * v04 + w1 * v14; aw5 += w0 * v05 + w1 * v15;
      aw6 += w0 * v06 + w1 * v16; aw7 += w0 * v07 + w1 * v17;
    }
    for (; k < nh; k++) {
      int2 p = ep[8 * k];
      uint4 r = X4[(unsigned)p.x * 8 + q];
      float w = __int_as_float(p.y);
      float v0 = BFLO(r.x), v1 = BFHI(r.x), v2 = BFLO(r.y), v3 = BFHI(r.y);
      float v4 = BFLO(r.z), v5 = BFHI(r.z), v6 = BFLO(r.w), v7 = BFHI(r.w);
      au0 += v0; au1 += v1; au2 += v2; au3 += v3; au4 += v4; au5 += v5; au6 += v6; au7 += v7;
      aw0 += w * v0; aw1 += w * v1; aw2 += w * v2; aw3 += w * v3;
      aw4 += w * v4; aw5 += w * v5; aw6 += w * v6; aw7 += w * v7;
    }
    au0 += __shfl_xor(au0, 8); au0 += __shfl_xor(au0, 16); au0 += __shfl_xor(au0, 32);
    au1 += __shfl_xor(au1, 8); au1 += __shfl_xor(au1, 16); au1 += __shfl_xor(au1, 32);
    au2 += __shfl_xor(au2, 8); au2 += __shfl_xor(au2, 16); au2 += __shfl_xor(au2, 32);
    au3 += __shfl_xor(au3, 8); au3 += __shfl_xor(au3, 16); au3 += __shfl_xor(au3, 32);
    au4 += __shfl_xor(au4, 8); au4 += __shfl_xor(au4, 16); au4 += __shfl_xor(au4, 32);
    au5 += __shfl_xor(au5, 8); au5 += __shfl_xor(au5, 16); au5 += __shfl_xor(au5, 32);
    au6 += __shfl_xor(au6, 8); au6 += __shfl_xor(au6, 16); au6 += __shfl_xor(au6, 32);
    au7 += __shfl_xor(au7, 8); au7 += __shfl_xor(au7, 16); au7 += __shfl_xor(au7, 32);
    aw0 += __shfl_xor(aw0, 8); aw0 += __shfl_xor(aw0, 16); aw0 += __shfl_xor(aw0, 32);
    aw1 += __shfl_xor(aw1, 8); aw1 += __shfl_xor(aw1, 16); aw1 += __shfl_xor(aw1, 32);
    aw2 += __shfl_xor(aw2, 8); aw2 += __shfl_xor(aw2, 16); aw2 += __shfl_xor(aw2, 32);
    aw3 += __shfl_xor(aw3, 8); aw3 += __shfl_xor(aw3, 16); aw3 += __shfl_xor(aw3, 32);
    aw4 += __shfl_xor(aw4, 8); aw4 += __shfl_xor(aw4, 16); aw4 += __shfl_xor(aw4, 32);
    aw5 += __shfl_xor(aw5, 8); aw5 += __shfl_xor(aw5, 16); aw5 += __shfl_xor(aw5, 32);
    aw6 += __shfl_xor(aw6, 8); aw6 += __shfl_xor(aw6, 16); aw6 += __shfl_xor(aw6, 32);
    aw7 += __shfl_xor(aw7, 8); aw7 += __shfl_xor(aw7, 16); aw7 += __shfl_xor(aw7, 32);
    if (h == 0) {
      ((float4*)outw)[wid * 16 + 2 * q]     = make_float4(aw0, aw1, aw2, aw3);
      ((float4*)outw)[wid * 16 + 2 * q + 1] = make_float4(aw4, aw5, aw6, aw7);
      ((float4*)outu)[wid * 16 + 2 * q]     = make_float4(au0, au1, au2, au3);
      ((float4*)outu)[wid * 16 + 2 * q + 1] = make_float4(au4, au5, au6, au7);
    }
  } else {
    int wid = (bb - nb64) * 4 + (threadIdx.x >> 6);
    if (wid >= NSV) return;
    int rs = rs_in[wid], c = cnt_in[wid];
    int nh = (c - h + 7) >> 3;
    const int* sp = srcs_in + rs + h;
    float a0 = 0.f, a1 = 0.f, a2 = 0.f, a3 = 0.f, a4 = 0.f, a5 = 0.f, a6 = 0.f, a7 = 0.f;
    int k = 0;
    for (; k + 2 <= nh; k += 2) {
      int s0 = sp[8 * k], s1 = sp[8 * k + 8];
      uint4 r0 = X4[(unsigned)s0 * 8 + q];
      uint4 r1 = X4[(unsigned)s1 * 8 + q];
      a0 += BFLO(r0.x) + BFLO(r1.x); a1 += BFHI(r0.x) + BFHI(r1.x);
      a2 += BFLO(r0.y) + BFLO(r1.y); a3 += BFHI(r0.y) + BFHI(r1.y);
      a4 += BFLO(r0.z) + BFLO(r1.z); a5 += BFHI(r0.z) + BFHI(r1.z);
      a6 += BFLO(r0.w) + BFLO(r1.w); a7 += BFHI(r0.w) + BFHI(r1.w);
    }
    for (; k < nh; k++) {
      uint4 r = X4[(unsigned)sp[8 * k] * 8 + q];
      a0 += BFLO(r.x); a1 += BFHI(r.x); a2 += BFLO(r.y); a3 += BFHI(r.y);
      a4 += BFLO(r.z); a5 += BFHI(r.z); a6 += BFLO(r.w); a7 += BFHI(r.w);
    }
    a0 += __shfl_xor(a0, 8); a0 += __shfl_xor(a0, 16); a0 += __shfl_xor(a0, 32);
    a1 += __shfl_xor(a1, 8); a1 += __shfl_xor(a1, 16); a1 += __shfl_xor(a1, 32);
    a2 += __shfl_xor(a2, 8); a2 += __shfl_xor(a2, 16); a2 += __shfl_xor(a2, 32);
    a3 += __shfl_xor(a3, 8); a3 += __shfl_xor(a3, 16); a3 += __shfl_xor(a3, 32);
    a4 += __shfl_xor(a4, 8); a4 += __shfl_xor(a4, 16); a4 += __shfl_xor(a4, 32);
    a5 += __shfl_xor(a5, 8); a5 += __shfl_xor(a5, 16); a5 += __shfl_xor(a5, 32);
    a6 += __shfl_xor(a6, 8); a6 += __shfl_xor(a6, 16); a6 += __shfl_xor(a6, 32);
    a7 += __shfl_xor(a7, 8); a7 += __shfl_xor(a7, 16); a7 += __shfl_xor(a7, 32);
    if (h == 0) {
      ((float4*)outIN)[wid * 16 + 2 * q]     = make_float4(a0, a1, a2, a3);
      ((float4*)outIN)[wid * 16 + 2 * q + 1] = make_float4(a4, a5, a6, a7);
    }
  }
}

__global__ __launch_bounds__(256)
void k_agg64b(const unsigned short* __restrict__ X16,
              const int* __restrict__ rowstart, const int* __restrict__ cnt,
              const int* __restrict__ srcs, float* __restrict__ out, int n) {
  const uint4* X4 = (const uint4*)X16;
  int wid = blockIdx.x * 4 + (threadIdx.x >> 6);
  if (wid >= n) return;
  int lane = threadIdx.x & 63;
  int q = lane & 7;
  int h = lane >> 3;
  int rs = rowstart[wid], c = cnt[wid];
  int nh = (c - h + 7) >> 3;
  const int* sp = srcs + rs + h;
  float a0 = 0.f, a1 = 0.f, a2 = 0.f, a3 = 0.f, a4 = 0.f, a5 = 0.f, a6 = 0.f, a7 = 0.f;
  int k = 0;
  for (; k + 2 <= nh; k += 2) {
    int s0 = sp[8 * k], s1 = sp[8 * k + 8];
    uint4 r0 = X4[(unsigned)s0 * 8 + q];
    uint4 r1 = X4[(unsigned)s1 * 8 + q];
    a0 += BFLO(r0.x) + BFLO(r1.x); a1 += BFHI(r0.x) + BFHI(r1.x);
    a2 += BFLO(r0.y) + BFLO(r1.y); a3 += BFHI(r0.y) + BFHI(r1.y);
    a4 += BFLO(r0.z) + BFLO(r1.z); a5 += BFHI(r0.z) + BFHI(r1.z);
    a6 += BFLO(r0.w) + BFLO(r1.w); a7 += BFHI(r0.w) + BFHI(r1.w);
  }
  for (; k < nh; k++) {
    uint4 r = X4[(unsigned)sp[8 * k] * 8 + q];
    a0 += BFLO(r.x); a1 += BFHI(r.x); a2 += BFLO(r.y); a3 += BFHI(r.y);
    a4 += BFLO(r.z); a5 += BFHI(r.z); a6 += BFLO(r.w); a7 += BFHI(r.w);
  }
  a0 += __shfl_xor(a0, 8); a0 += __shfl_xor(a0, 16); a0 += __shfl_xor(a0, 32);
  a1 += __shfl_xor(a1, 8); a1 += __shfl_xor(a1, 16); a1 += __shfl_xor(a1, 32);
  a2 += __shfl_xor(a2, 8); a2 += __shfl_xor(a2, 16); a2 += __shfl_xor(a2, 32);
  a3 += __shfl_xor(a3, 8); a3 += __shfl_xor(a3, 16); a3 += __shfl_xor(a3, 32);
  a4 += __shfl_xor(a4, 8); a4 += __shfl_xor(a4, 16); a4 += __shfl_xor(a4, 32);
  a5 += __shfl_xor(a5, 8); a5 += __shfl_xor(a5, 16); a5 += __shfl_xor(a5, 32);
  a6 += __shfl_xor(a6, 8); a6 += __shfl_xor(a6, 16); a6 += __shfl_xor(a6, 32);
  a7 += __shfl_xor(a7, 8); a7 += __shfl_xor(a7, 16); a7 += __shfl_xor(a7, 32);
  if (h == 0) {
    ((float4*)out)[wid * 16 + 2 * q]     = make_float4(a0, a1, a2, a3);
    ((float4*)out)[wid * 16 + 2 * q + 1] = make_float4(a4, a5, a6, a7);
  }
}

// prescaled TAG hop: U = dinv ⊙ t (bf16). t_out = dinv[d]*Σ U[s]; u_out = dinv[d]*t_out.
__global__ __launch_bounds__(256)
void k_tag64b(const unsigned short* __restrict__ U16,
              const int* __restrict__ rowstart, const int* __restrict__ cnt,
              const int* __restrict__ srcs, const float* __restrict__ dinv,
              unsigned short* __restrict__ t_out, unsigned short* __restrict__ u_out, int n) {
  const uint4* X4 = (const uint4*)U16;
  int wid = blockIdx.x * 4 + (threadIdx.x >> 6);
  if (wid >= n) return;
  int lane = threadIdx.x & 63;
  int q = lane & 7;
  int h = lane >> 3;
  int rs = rowstart[wid], c = cnt[wid];
  int nh = (c - h + 7) >> 3;
  const int* sp = srcs + rs + h;
  float a0 = 0.f, a1 = 0.f, a2 = 0.f, a3 = 0.f, a4 = 0.f, a5 = 0.f, a6 = 0.f, a7 = 0.f;
  int k = 0;
  for (; k + 2 <= nh; k += 2) {
    int s0 = sp[8 * k], s1 = sp[8 * k + 8];
    uint4 r0 = X4[(unsigned)s0 * 8 + q];
    uint4 r1 = X4[(unsigned)s1 * 8 + q];
    a0 += BFLO(r0.x) + BFLO(r1.x); a1 += BFHI(r0.x) + BFHI(r1.x);
    a2 += BFLO(r0.y) + BFLO(r1.y); a3 += BFHI(r0.y) + BFHI(r1.y);
    a4 += BFLO(r0.z) + BFLO(r1.z); a5 += BFHI(r0.z) + BFHI(r1.z);
    a6 += BFLO(r0.w) + BFLO(r1.w); a7 += BFHI(r0.w) + BFHI(r1.w);
  }
  for (; k < nh; k++) {
    uint4 r = X4[(unsigned)sp[8 * k] * 8 + q];
    a0 += BFLO(r.x); a1 += BFHI(r.x); a2 += BFLO(r.y); a3 += BFHI(r.y);
    a4 += BFLO(r.z); a5 += BFHI(r.z); a6 += BFLO(r.w); a7 += BFHI(r.w);
  }
  a0 += __shfl_xor(a0, 8); a0 += __shfl_xor(a0, 16); a0 += __shfl_xor(a0, 32);
  a1 += __shfl_xor(a1, 8); a1 += __shfl_xor(a1, 16); a1 += __shfl_xor(a1, 32);
  a2 += __shfl_xor(a2, 8); a2 += __shfl_xor(a2, 16); a2 += __shfl_xor(a2, 32);
  a3 += __shfl_xor(a3, 8); a3 += __shfl_xor(a3, 16); a3 += __shfl_xor(a3, 32);
  a4 += __shfl_xor(a4, 8); a4 += __shfl_xor(a4, 16); a4 += __shfl_xor(a4, 32);
  a5 += __shfl_xor(a5, 8); a5 += __shfl_xor(a5, 16); a5 += __shfl_xor(a5, 32);
  a6 += __shfl_xor(a6, 8); a6 += __shfl_xor(a6, 16); a6 += __shfl_xor(a6, 32);
  a7 += __shfl_xor(a7, 8); a7 += __shfl_xor(a7, 16); a7 += __shfl_xor(a7, 32);
  if (h == 0) {
    float dv = dinv[wid];
    float t0 = dv * a0, t1 = dv * a1, t2 = dv * a2, t3 = dv * a3;
    float t4 = dv * a4, t5 = dv * a5, t6 = dv * a6, t7 = dv * a7;
    ((uint4*)t_out)[wid * 8 + q] =
        make_uint4(PK2(t0, t1), PK2(t2, t3), PK2(t4, t5), PK2(t6, t7));
    if (u_out)
      ((uint4*)u_out)[wid * 8 + q] =
          make_uint4(PK2(dv * t0, dv * t1), PK2(dv * t2, dv * t3),
                     PK2(dv * t4, dv * t5), PK2(dv * t6, dv * t7));
  }
}

// ====================== Fused MM building blocks (256 threads, 4 nodes x 4 feats) ======================
// NOTE (r12-r14): 512-thread variants produced ~2-4 GB phantom scratch traffic. Keep 256.
// NOTE (R1): named-register T14 queues + __launch_bounds__(256,3) — do not revert to arrays.
// NOTE (R6): R3's scalar mm_acc (broadcast A-reads) is the verified-best form.
// NOTE (R8): do not fuse row-gathers into MM-tile-sized grids (R7: 16x TLP loss).

__device__ __forceinline__ void mm_zero(float acc[4][4]) {
#pragma unroll
  for (int j = 0; j < 4; j++)
#pragma unroll
    for (int jj = 0; jj < 4; jj++) acc[j][jj] = 0.f;
}

__device__ __forceinline__ void mm_acc(const float* sA, const float* sW, int K,
                                       int nl0, int f0, float acc[4][4]) {
  for (int k = 0; k < K; k++) {
    float4 w = *(const float4*)(&sW[k * 64 + f0]);
#pragma unroll
    for (int j = 0; j < 4; j++) {
      float a = sA[(nl0 + j) * 68 + k];
      acc[j][0] += a * w.x; acc[j][1] += a * w.y; acc[j][2] += a * w.z; acc[j][3] += a * w.w;
    }
  }
}

// ---- named-register staging queue (single set live at a time) ----
#define WQ_ISSUE(W) do { const float4* _w = (const float4*)(W); \
  sw0 = _w[tid]; sw1 = _w[tid + 256]; sw2 = _w[tid + 512]; sw3 = _w[tid + 768]; } while (0)

#define WQ_COMMIT() do { float4* _s = (float4*)Ws; \
  _s[tid] = sw0; _s[tid + 256] = sw1; _s[tid + 512] = sw2; _s[tid + 768] = sw3; } while (0)

#define AQ_ISSUE1_F32(A, CNT, aa, cc, I) do { int _idx = tid + (I) * 256; \
  int _nl = _idx >> 4, _k4 = _idx & 15; int _g = gb + _nl; bool _ok = _g < n; \
  (aa) = _ok ? ((const float4*)(A))[_g * 16 + _k4] : make_float4(0.f, 0.f, 0.f, 0.f); \
  (cc) = ((CNT) != nullptr && _ok) ? (float)(CNT)[_g] : 1.f; } while (0)

#define AQ_ISSUE_F32(A, CNT) do { \
  AQ_ISSUE1_F32(A, CNT, sa0, sc0, 0); AQ_ISSUE1_F32(A, CNT, sa1, sc1, 1); \
  AQ_ISSUE1_F32(A, CNT, sa2, sc2, 2); AQ_ISSUE1_F32(A, CNT, sa3, sc3, 3); } while (0)

#define AQ_COMMIT1_F32(DST, SC, aa, cc, I) do { int _idx = tid + (I) * 256; \
  int _nl = _idx >> 4, _k4 = _idx & 15; float4 _v = (aa); \
  if (SC) { float _m = 1.f / fmaxf((cc), 1.f); _v.x *= _m; _v.y *= _m; _v.z *= _m; _v.w *= _m; } \
  *(float4*)(&(DST)[_nl * 68 + _k4 * 4]) = _v; } while (0)

#define AQ_COMMIT_F32(DST, SC) do { \
  AQ_COMMIT1_F32(DST, SC, sa0, sc0, 0); AQ_COMMIT1_F32(DST, SC, sa1, sc1, 1); \
  AQ_COMMIT1_F32(DST, SC, sa2, sc2, 2); AQ_COMMIT1_F32(DST, SC, sa3, sc3, 3); } while (0)

#define AQ_ISSUE1_BF16(A, bb, I) do { int _idx = tid + (I) * 256; \
  int _nl = _idx >> 4, _k4 = _idx & 15; int _g = gb + _nl; \
  (bb) = (_g < n) ? ((const uint2*)((A) + (size_t)_g * 64))[_k4] : make_uint2(0u, 0u); } while (0)

#define AQ_ISSUE_BF16(A) do { \
  AQ_ISSUE1_BF16(A, sb0, 0); AQ_ISSUE1_BF16(A, sb1, 1); \
  AQ_ISSUE1_BF16(A, sb2, 2); AQ_ISSUE1_BF16(A, sb3, 3); } while (0)

#define AQ_COMMIT1_BF16(bb, I) do { int _idx = tid + (I) * 256; \
  int _nl = _idx >> 4, _k4 = _idx & 15; float4 _v; \
  _v.x = bf2f((unsigned short)((bb).x & 0xFFFF)); \
  _v.y = bf2f((unsigned short)((bb).x >> 16)); \
  _v.z = bf2f((unsigned short)((bb).y & 0xFFFF)); \
  _v.w = bf2f((unsigned short)((bb).y >> 16)); \
  *(float4*)(&as[_nl * 68 + _k4 * 4]) = _v; } while (0)

#define AQ_COMMIT_BF16() do { \
  AQ_COMMIT1_BF16(sb0, 0); AQ_COMMIT1_BF16(sb1, 1); \
  AQ_COMMIT1_BF16(sb2, 2); AQ_COMMIT1_BF16(sb3, 3); } while (0)

// ---- phase-C chain: S2 = relu(aggIN'@W42_l + relu(aggIN'@W4_l + relu(aggHu'@W32_l +
//      relu(aggHw@W3_rel + sx@W3_root + b3)@W32_r + b32)@W4_r + b4)@W42_r + b42) ----
__global__ __launch_bounds__(256, 3)
void k_mm_chainC(const float* __restrict__ aggHw, const float* __restrict__ state_x,
                 const float* __restrict__ aggHu, const int* __restrict__ cnt_h,
                 const float* __restrict__ aggIN, const int* __restrict__ cnt_in,
                 const float* __restrict__ W3_rel, const float* __restrict__ W3_root,
                 const float* __restrict__ b3,
                 const float* __restrict__ W32_l, const float* __restrict__ W32_r,
                 const float* __restrict__ b32,
                 const float* __restrict__ W4_l, const float* __restrict__ W4_r,
                 const float* __restrict__ b4,
                 const float* __restrict__ W42_l, const float* __restrict__ W42_r,
                 const float* __restrict__ b42,
                 float* __restrict__ S2out, unsigned short* __restrict__ S2b,
                 const float* __restrict__ dinvS, int n) {
  __shared__ float Ws[4096];
  __shared__ float as[64 * 68];
  __shared__ float cs[64 * 68];
  const int tid = threadIdx.x;
  const int gb = blockIdx.x * 64;
  const int lane = tid & 63;
  const int fq = lane & 15, nq = lane >> 4;
  const int f0 = fq * 4;
  const int nl0 = (tid >> 6) * 16 + nq * 4;
  float acc[4][4];
  float4 sw0, sw1, sw2, sw3, sa0, sa1, sa2, sa3;
  float sc0, sc1, sc2, sc3;

  // ---- prologue: stage1 + all small scalars ----
  WQ_ISSUE(W3_rel);
  AQ_ISSUE_F32(aggHw, (const int*)nullptr);
  float rt0 = W3_root[tid];
  float rt1 = (tid < 64) ? W3_root[256 + tid] : 0.f;
  const int nlA = tid / 5, kA = tid - nlA * 5;
  float sxA = (gb + nlA < n) ? state_x[(size_t)(gb + nlA) * 5 + kA] : 0.f;
  const int iB = tid + 256;
  const int nlB = iB / 5, kB = iB - nlB * 5;
  float sxB = (tid < 64 && gb + nlB < n) ? state_x[(size_t)(gb + nlB) * 5 + kB] : 0.f;
  float4 rb3  = ((const float4*)b3)[fq];
  float4 rb32 = ((const float4*)b32)[fq];
  float4 rb4  = ((const float4*)b4)[fq];
  float4 rb42 = ((const float4*)b42)[fq];
  float rdv[4];
#pragma unroll
  for (int j = 0; j < 4; j++) {
    int g = gb + nl0 + j;
    rdv[j] = (g < n) ? dinvS[g] : 0.f;
  }
  WQ_COMMIT();                       // Ws <- W3_rel
  AQ_COMMIT_F32(as, false);          // as <- aggHw
  __syncthreads();

  // ---- phase 1: C1a + C1b ----
  WQ_ISSUE(W32_l);
  AQ_ISSUE_F32(aggHu, cnt_h);        // in flight under C1a+C1b
  mm_zero(acc);
  mm_acc(as, Ws, 64, nl0, f0, acc);  // C1a: aggHw @ W3_rel
  __syncthreads();
  Ws[tid] = rt0;                     // small commit: W3_root, state_x
  if (tid < 64) Ws[256 + tid] = rt1;
  as[nlA * 68 + kA] = sxA;
  if (tid < 64) as[nlB * 68 + kB] = sxB;
  __syncthreads();
  mm_acc(as, Ws, 5, nl0, f0, acc);   // C1b: + state_x @ W3_root
  {
    float bb[4] = {rb3.x, rb3.y, rb3.z, rb3.w};
#pragma unroll
    for (int j = 0; j < 4; j++)
#pragma unroll
      for (int jj = 0; jj < 4; jj++)
        cs[(nl0 + j) * 68 + f0 + jj] = fmaxf(acc[j][jj] + bb[jj], 0.f);
  }
  __syncthreads();
  WQ_COMMIT();                       // Ws <- W32_l
  AQ_COMMIT_F32(as, true);           // as <- aggHu'
  __syncthreads();

  // ---- phase 2: C2a ----
  WQ_ISSUE(W32_r);                   // in flight under C2a
  mm_zero(acc);
  mm_acc(as, Ws, 64, nl0, f0, acc);  // aggHu' @ W32_l
  __syncthreads();
  WQ_COMMIT();                       // Ws <- W32_r
  __syncthreads();

  // ---- phase 3: C2b ----
  WQ_ISSUE(W4_l);
  AQ_ISSUE_F32(aggIN, cnt_in);       // in flight under C2b
  mm_acc(cs, Ws, 64, nl0, f0, acc);  // + h3 @ W32_r
  __syncthreads();
  {
    float bb[4] = {rb32.x, rb32.y, rb32.z, rb32.w};
#pragma unroll
    for (int j = 0; j < 4; j++)
#pragma unroll
      for (int jj = 0; jj < 4; jj++)
        cs[(nl0 + j) * 68 + f0 + jj] = fmaxf(acc[j][jj] + bb[jj], 0.f);
  }
  WQ_COMMIT();                       // Ws <- W4_l
  AQ_COMMIT_F32(as, true);           // as <- aggIN' (lives through C4a)
  __syncthreads();

  // ---- phase 4: C3a ----
  WQ_ISSUE(W4_r);
  mm_zero(acc);
  mm_acc(as, Ws, 64, nl0, f0, acc);  // aggIN' @ W4_l
  __syncthreads();
  WQ_COMMIT();                       // Ws <- W4_r
  __syncthreads();

  // ---- phase 5: C3b ----
  WQ_ISSUE(W42_l);
  mm_acc(cs, Ws, 64, nl0, f0, acc);  // + h32 @ W4_r
  __syncthreads();
  {
    float bb[4] = {rb4.x, rb4.y, rb4.z, rb4.w};
#pragma unroll
    for (int j = 0; j < 4; j++)
#pragma unroll
      for (int jj = 0; jj < 4; jj++)
        cs[(nl0 + j) * 68 + f0 + jj] = fmaxf(acc[j][jj] + bb[jj], 0.f);
  }
  WQ_COMMIT();                       // Ws <- W42_l
  __syncthreads();

  // ---- phase 6: C4a ----
  WQ_ISSUE(W42_r);
  mm_zero(acc);
  mm_acc(as, Ws, 64, nl0, f0, acc);  // aggIN' @ W42_l (as untouched since phase 3)
  __syncthreads();
  WQ_COMMIT();                       // Ws <- W42_r
  __syncthreads();

  // ---- phase 7: C4b + epilogue ----
  mm_acc(cs, Ws, 64, nl0, f0, acc);  // + h4 @ W42_r
  {
    float bb[4] = {rb42.x, rb42.y, rb42.z, rb42.w};
#pragma unroll
    for (int j = 0; j < 4; j++) {
      int g = gb + nl0 + j;
      if (g < n) {
        float osc = rdv[j];
#pragma unroll
        for (int jj = 0; jj < 4; jj++) {
          int f = f0 + jj;
          float v = fmaxf(acc[j][jj] + bb[jj], 0.f);
          S2out[(size_t)g * 64 + f] = v;
          S2b[(size_t)g * 64 + f] = f2bf(v * osc);
        }
      }
    }
  }
}

// ---- phase-D quad MM: S1 = relu(S2@W2_0 + t1@W2_1 + t2@W2_2 + t3@W2_3 + b2); S1b = bf16 ----
__global__ __launch_bounds__(256, 4)
void k_mm_d(const float* __restrict__ S2, const unsigned short* __restrict__ t1b,
            const unsigned short* __restrict__ t2b, const unsigned short* __restrict__ t3b,
            const float* __restrict__ W2, const float* __restrict__ b2,
            float* __restrict__ S1, unsigned short* __restrict__ S1b, int n) {
  __shared__ float Ws[4096];
  __shared__ float as[64 * 68];
  const int tid = threadIdx.x;
  const int gb = blockIdx.x * 64;
  const int lane = tid & 63;
  const int fq = lane & 15, nq = lane >> 4;
  const int f0 = fq * 4;
  const int nl0 = (tid >> 6) * 16 + nq * 4;
  float acc[4][4];
  float4 sw0, sw1, sw2, sw3, sa0, sa1, sa2, sa3;
  float sc0, sc1, sc2, sc3;
  uint2 sb0, sb1, sb2, sb3;

  // prologue: stage0 (W2_0, S2 f32)
  WQ_ISSUE(W2);
  AQ_ISSUE_F32(S2, (const int*)nullptr);
  float4 rb2 = ((const float4*)b2)[fq];
  WQ_COMMIT();
  AQ_COMMIT_F32(as, false);
  __syncthreads();

  // phase 1: op0 (S2 f32)
  WQ_ISSUE(W2 + 4096);
  AQ_ISSUE_BF16(t1b);
  mm_zero(acc);
  mm_acc(as, Ws, 64, nl0, f0, acc);
  __syncthreads();
  WQ_COMMIT();
  AQ_COMMIT_BF16();
  __syncthreads();

  // phase 2: op1 (t1)
  WQ_ISSUE(W2 + 8192);
  AQ_ISSUE_BF16(t2b);
  mm_acc(as, Ws, 64, nl0, f0, acc);
  __syncthreads();
  WQ_COMMIT();
  AQ_COMMIT_BF16();
  __syncthreads();

  // phase 3: op2 (t2)
  WQ_ISSUE(W2 + 12288);
  AQ_ISSUE_BF16(t3b);
  mm_acc(as, Ws, 64, nl0, f0, acc);
  __syncthreads();
  WQ_COMMIT();
  AQ_COMMIT_BF16();
  __syncthreads();

  // phase 4: op3 (t3) + epilogue
  mm_acc(as, Ws, 64, nl0, f0, acc);
  {
    float bb[4] = {rb2.x, rb2.y, rb2.z, rb2.w};
#pragma unroll
    for (int j = 0; j < 4; j++) {
      int g = gb + nl0 + j;
      if (g < n) {
#pragma unroll
        for (int jj = 0; jj < 4; jj++) {
          int f = f0 + jj;
          float v = fmaxf(acc[j][jj] + bb[jj], 0.f);
          S1[(size_t)g * 64 + f] = v;
          S1b[(size_t)g * 64 + f] = f2bf(v);
        }
      }
    }
  }
}

// ---- phase-E MM + final projection: out = relu(aggSS'@W5_l + S1@W5_r + b5) @ Wl + bl ----
__global__ __launch_bounds__(256, 3)
void k_mm_e(const float* __restrict__ aggSS, const int* __restrict__ cnt_ss,
            const float* __restrict__ W5_l, const float* __restrict__ S1,
            const float* __restrict__ W5_r, const float* __restrict__ b5,
            const float* __restrict__ Wl, const float* __restrict__ bl,
            float* __restrict__ out, int n) {
  __shared__ float Ws[4096];
  __shared__ float as[64 * 68];
  __shared__ float cs[64 * 68];
  const int tid = threadIdx.x;
  const int gb = blockIdx.x * 64;
  const int lane = tid & 63;
  const int fq = lane & 15, nq = lane >> 4;
  const int f0 = fq * 4;
  const int nl0 = (tid >> 6) * 16 + nq * 4;
  float acc[4][4];
  float4 sw0, sw1, sw2, sw3, sa0, sa1, sa2, sa3;
  float sc0, sc1, sc2, sc3;

  // prologue: stage0 (W5_l, aggSS') + projection scalars
  WQ_ISSUE(W5_l);
  AQ_ISSUE_F32(aggSS, cnt_ss);
  float rwl0 = Wl[tid];
  float rwl1 = Wl[256 + tid];
  float4 rb5 = ((const float4*)b5)[fq];
  float rbl0 = bl[(2 * tid) & 7];
  float rbl1 = bl[(2 * tid + 1) & 7];
  WQ_COMMIT();
  AQ_COMMIT_F32(as, true);
  __syncthreads();

  // phase 1: aggSS' @ W5_l
  WQ_ISSUE(W5_r);
  AQ_ISSUE_F32(S1, (const int*)nullptr);
  mm_zero(acc);
  mm_acc(as, Ws, 64, nl0, f0, acc);
  __syncthreads();
  WQ_COMMIT();                       // Ws <- W5_r
  AQ_COMMIT_F32(cs, false);          // cs <- S1
  __syncthreads();

  // phase 2: + S1 @ W5_r, then project
  mm_acc(cs, Ws, 64, nl0, f0, acc);
  __syncthreads();
  {
    float bb[4] = {rb5.x, rb5.y, rb5.z, rb5.w};
#pragma unroll
    for (int j = 0; j < 4; j++)
#pragma unroll
      for (int jj = 0; jj < 4; jj++)
        as[(nl0 + j) * 68 + f0 + jj] = fmaxf(acc[j][jj] + bb[jj], 0.f);
  }
  Ws[tid] = rwl0;
  Ws[256 + tid] = rwl1;
  __syncthreads();
#pragma unroll
  for (int p = 0; p < 2; p++) {
    int idx = tid * 2 + p;
    int nl = idx >> 3, o = idx & 7;
    int g = gb + nl;
    if (g < n) {
      float a2 = (p == 0) ? rbl0 : rbl1;
#pragma unroll 8
      for (int k = 0; k < 64; k++) a2 += as[nl * 68 + k] * Ws[k * 8 + o];
      out[(size_t)g * 8 + o] = a2;
    }
  }
}

// ---------------- Host ----------------

extern "C" void kernel_launch(void* const* d_in, const int* in_sizes, int n_in,
                              void* d_out, int out_size, void* d_ws, size_t ws_size,
                              hipStream_t stream) {
  const float* game_x  = (const float*)d_in[0];
  const float* state_x = (const float*)d_in[1];
  const int*   ei_vv   = (const int*)d_in[2];
  const int*   et_vv   = (const int*)d_in[3];
  const int*   ei_h    = (const int*)d_in[4];
  const float* ew_h    = (const float*)d_in[5];
  const int*   ei_in   = (const int*)d_in[6];
  const int*   ei_ss   = (const int*)d_in[7];
  const float* W1_rel  = (const float*)d_in[8];
  const float* W1_root = (const float*)d_in[9];
  const float* b1      = (const float*)d_in[10];
  const float* W12     = (const float*)d_in[11];
  const float* b12     = (const float*)d_in[12];
  const float* W2      = (const float*)d_in[13];
  const float* b2      = (const float*)d_in[14];
  const float* W3_rel  = (const float*)d_in[15];
  const float* W3_root = (const float*)d_in[16];
  const float* b3      = (const float*)d_in[17];
  const float* W32_l   = (const float*)d_in[18];
  const float* W32_r   = (const float*)d_in[19];
  const float* b32     = (const float*)d_in[20];
  const float* W4_l    = (const float*)d_in[21];
  const float* W4_r    = (const float*)d_in[22];
  const float* b4      = (const float*)d_in[23];
  const float* W42_l   = (const float*)d_in[24];
  const float* W42_r   = (const float*)d_in[25];
  const float* b42     = (const float*)d_in[26];
  const float* W5_l    = (const float*)d_in[27];
  const float* W5_r    = (const float*)d_in[28];
  const float* b5      = (const float*)d_in[29];
  const float* Wl      = (const float*)d_in[30];
  const float* bl      = (const float*)d_in[31];

  // Workspace (4B slots), peak 26.05M slots = 104.2 MiB.
  float* ws = (float*)d_ws;
  int*   cnt_all = (int*)(ws + 0);              // 250K (vv|h|in|ss)
  int*   rs_all  = (int*)(ws + 250000);         // 250K (graph-local values)
  int*   bcnt    = (int*)(ws + 500000);         // 512
  int*   bbase   = (int*)(ws + 500512);         // 512
  int*   cb      = (int*)(ws + 501024);         // 512
  int*   srcs_ss = (int*)(ws + 760000);         // 0.8M  (lives through phase E)
  float4* x_pad  = (float4*)(ws + 1600000);     // 800K
  float4* h1p    = (float4*)(ws + 2400000);
  float4* h2p    = (float4*)(ws + 3200000);
  float4* h3p    = (float4*)(ws + 4000000);
  float4* ra4all = (float4*)(ws + 4800000);     // [NVV][5] float4 = 2.0M slots -> 6.8M
  float* dinvS   = ws + 6800000;                // 50K
  unsigned short* gx16 = (unsigned short*)(ws + 6850000);  // 3.2M slots -> 10.05M
  unsigned* temp_vv    = (unsigned*)(ws + 6850000);        // 1.6M, overlays gx16 front (dead before combine)
  float* aggHw = ws + 10050000;                 // 3.2M
  float* aggHu = ws + 13250000;                 // 3.2M
  float* aggIN = ws + 16450000;                 // 3.2M
  float* S1    = ws + 19650000;                 // 3.2M
  float* S2    = ws + 22850000;                 // 3.2M -> ends 26.05M
  // fill temps overlay agg regions (dead until phase B):
  uint2*    temp_h  = (uint2*)aggHw;
  unsigned* temp_in = (unsigned*)(aggHw + 1600000);
  unsigned* temp_ss = (unsigned*)(aggHw + 2400000);
  // overlays (dead-before-write verified in stream order):
  unsigned short* S2b = (unsigned short*)(ws + 4800000);     // in ra4all region (dead after combine_gx)
  unsigned short* u1b = (unsigned short*)(aggHw + 1600000);  // hop1 aux; aggHw dead after chainC
  float*          aggSS = aggHw + 1600000;                   // phase E (after u1b dead)
  unsigned short* t1b = (unsigned short*)aggHu;              // aggHu dead after chainC
  unsigned short* t2b = (unsigned short*)(aggHu + 1600000);
  unsigned short* t3b = (unsigned short*)aggIN;              // aggIN dead after chainC
  unsigned short* S1b = (unsigned short*)(aggIN + 1600000);  // k_mm_d shadow
  unsigned* payload_vv = (unsigned*)S1;                      // dead after phase A
  unsigned short* u2b  = (unsigned short*)S1;                // hop2 aux; S1 written later by k_mm_d
  int2*     eh         = (int2*)S2;                          // dead after aggB; S2 written by chainC
  int*      srcs_in    = (int*)(S2 + 1600000);

  const int* src_vv = ei_vv;  const int* dst_vv = ei_vv + E_VV;
  const int* src_h  = ei_h;   const int* dst_h  = ei_h + E_H;
  const int* src_in = ei_in;  const int* dst_in = ei_in + E_IN;
  const int* src_ss = ei_ss;  const int* dst_ss = ei_ss + E_SS;

  auto nblk = [](long long n) { return dim3((unsigned)((n + 255) / 256)); };
  const int NB64 = (NSV + 3) / 4;
  const int NB   = (NSV + 63) / 64;
  const int GC   = (ETOT + TC - 1) / TC;
  const int NBVV4 = (NVV + 63) / 64;   // 4 lanes/node vv kernels

  int* cnt_h  = cnt_all + H_ROW;
  int* cnt_in = cnt_all + IN_ROW;
  int* cnt_ss = cnt_all + SS_ROW;
  int* rs_vv  = rs_all;
  int* rs_h   = rs_all + H_ROW;
  int* rs_in  = rs_all + IN_ROW;
  int* rs_ss  = rs_all + SS_ROW;

  // ---- CSR build (fused) ----
  hipMemsetAsync(bcnt, 0, NBTOT * sizeof(int), stream);
  k_bucket_count<<<GC, 256, 0, stream>>>(dst_vv, dst_h, dst_in, dst_ss, bcnt);
  k_bucket_scan<<<1, 512, 0, stream>>>(bcnt, bbase, cb);
  k_fill_s1_all<<<SB1, 256, 0, stream>>>(src_vv, dst_vv, et_vv, src_h, dst_h, ew_h,
                                         src_in, dst_in, src_ss, dst_ss, cb,
                                         temp_vv, temp_h, temp_in, temp_ss);
  k_fill_s2_all<<<NBTOT, 256, 0, stream>>>(temp_vv, temp_h, temp_in, temp_ss, bbase,
                                           payload_vv, eh, srcs_in, srcs_ss,
                                           rs_all, cnt_all, game_x, x_pad, dinvS);

  // ---- Phase A: v-graph 5-dim (4 lanes/node) ----
  k_vv_pass1<<<NBVV4, 256, 0, stream>>>(x_pad, rs_vv, cnt_all, payload_vv, ra4all, h1p);
  k_vv_hop<<<NBVV4, 256, 0, stream>>>(h1p, rs_vv, cnt_all, payload_vv, h2p);
  k_vv_hop<<<NBVV4, 256, 0, stream>>>(h2p, rs_vv, cnt_all, payload_vv, h3p);
  k_combine_gx<<<dim3((NVV + 31) / 32), 256, 0, stream>>>(x_pad, ra4all, h1p, h2p, h3p,
                                                          W1_rel, W1_root, b1, W12, b12, gx16);

  // ---- Phase B: fused 64-dim bf16 gathers ----
  k_aggB<<<2 * NB64, 256, 0, stream>>>(gx16, rs_h, cnt_h, eh, rs_in, cnt_in, srcs_in,
                                       aggHw, aggHu, aggIN, NB64);

  // ---- Phase C: fused 4-MM chain -> S2 (+ dinv-prescaled bf16 shadow) ----
  k_mm_chainC<<<NB, 256, 0, stream>>>(aggHw, state_x, aggHu, cnt_h, aggIN, cnt_in,
                                      W3_rel, W3_root, b3, W32_l, W32_r, b32,
                                      W4_l, W4_r, b4, W42_l, W42_r, b42,
                                      S2, S2b, dinvS, NSV);

  // ---- Phase D: TAG on s-s (prescaled bf16 hops) + fused quad MM ----
  k_tag64b<<<NB64, 256, 0, stream>>>(S2b, rs_ss, cnt_ss, srcs_ss, dinvS, t1b, u1b, NSV);
  k_tag64b<<<NB64, 256, 0, stream>>>(u1b, rs_ss, cnt_ss, srcs_ss, dinvS, t2b, u2b, NSV);
  k_tag64b<<<NB64, 256, 0, stream>>>(u2b, rs_ss, cnt_ss, srcs_ss, dinvS, t3b, nullptr, NSV);
  k_mm_d<<<NB, 256, 0, stream>>>(S2, t1b, t2b, t3b, W2, b2, S1, S1b, NSV);

  // ---- Phase E: SAGE on s-s + final projection ----
  k_agg64b<<<NB64, 256, 0, stream>>>(S1b, rs_ss, cnt_ss, srcs_ss, aggSS, NSV);
  k_mm_e<<<NB, 256, 0, stream>>>(aggSS, cnt_ss, W5_l, S1, W5_r, b5, Wl, bl, (float*)d_out, NSV);
}